// Round 10
// baseline (578.337 us; speedup 1.0000x reference)
//
#include <hip/hip_runtime.h>
#include <math.h>

// R9: 408us. attn 227us, VALUBusy 60% — LDS-issue-bound: 2304 broadcast
// ds_read_b128/wave x ~12cyc ≈ 208us/CU. Non-attn residue 181us (projcomp 72
// blocks). R10: R=4 queries/lane (LDS/pair /4), no-max softmax (scores
// bounded) + fp32 atomicAdd merge (no barriers, private LDS quadrants),
// Q precomputed bf16 [h][n][8] coalesced layout, proj+compress collapsed into
// one K=64x2 GEMM via precomputed W1=Wc_r*Wrp, W2=Wc_d*Wdp.
#define BATCH 2
#define C 64
#define HH 48
#define WW 48
#define NTOK 2304
#define HEADS 8
#define KVSTRIDE 12

typedef unsigned short bf16_t;
__device__ __forceinline__ bf16_t f2bf(float f) {
    unsigned int u = __float_as_uint(f);
    u = (u + 0x7fffu + ((u >> 16) & 1u)) >> 16;   // RNE
    return (bf16_t)u;
}
__device__ __forceinline__ unsigned pack2(float a, float b) {
    return (unsigned)f2bf(a) | ((unsigned)f2bf(b) << 16);
}
__device__ __forceinline__ float4 ld_bf4(const bf16_t* p) {
    uint2 v = *(const uint2*)p;
    float4 r;
    r.x = __uint_as_float(v.x << 16); r.y = __uint_as_float(v.x & 0xffff0000u);
    r.z = __uint_as_float(v.y << 16); r.w = __uint_as_float(v.y & 0xffff0000u);
    return r;
}

// Stage one token-row of X. strm 0: rgb transpose gather. strm 1: conv1x1+
// ReLU+bilinear x2 (half-pixel; clamp == jax edge renorm for 24->48).
__device__ __forceinline__ void stage_x_row(
    float* xrow, const float* rgb, const float* dep,
    const float* w_exp, const float* b_exp,
    int b, int n, int strm, int c0, int cstep)
{
    int wi = n / HH, hi = n % HH;
    if (strm == 0) {
        const float* base = rgb + (size_t)b * C * NTOK + (size_t)hi * WW + wi;
        for (int c = c0; c < 64; c += cstep)
            xrow[c] = base[(size_t)c * NTOK];
    } else {
        float cy = 0.5f * hi - 0.25f, cx = 0.5f * wi - 0.25f;
        float fy0 = floorf(cy), fx0 = floorf(cx);
        float fy = cy - fy0, fx = cx - fx0;
        int y0 = max((int)fy0, 0), x0 = max((int)fx0, 0);
        int y1 = min((int)fy0 + 1, 23), x1 = min((int)fx0 + 1, 23);
        const float* dp = dep + b * 576;
        float d00 = dp[y0*24 + x0], d01 = dp[y0*24 + x1];
        float d10 = dp[y1*24 + x0], d11 = dp[y1*24 + x1];
        for (int c = c0; c < 64; c += cstep) {
            float w = w_exp[c], bb = b_exp[c];
            float r00 = fmaxf(w*d00 + bb, 0.f), r01 = fmaxf(w*d01 + bb, 0.f);
            float r10 = fmaxf(w*d10 + bb, 0.f), r11 = fmaxf(w*d11 + bb, 0.f);
            xrow[c] = (1.f-fy)*((1.f-fx)*r00 + fx*r01) + fy*((1.f-fx)*r10 + fx*r11);
        }
    }
}

// ===========================================================================
// NEW PATH (ws >= 6,226,176 B)
// ===========================================================================

__global__ __launch_bounds__(256) void zero_kernel(float4* __restrict__ p, int n4)
{
    int i = blockIdx.x * 256 + threadIdx.x;
    if (i < n4) p[i] = make_float4(0.f, 0.f, 0.f, 0.f);
}

// W1 = Wc[:, :64] @ Wrp ; W2 = Wc[:, 64:] @ Wdp ; beff = Wc@[br;bd] + bc.
// grid(4, 2): 16 output rows per block, m = which half.
__global__ __launch_bounds__(256) void wprep_kernel(
    const float* __restrict__ w_rp, const float* __restrict__ w_dp,
    const float* __restrict__ w_comp,
    const float* __restrict__ b_rp, const float* __restrict__ b_dp,
    const float* __restrict__ b_comp,
    float* __restrict__ W1, float* __restrict__ W2, float* __restrict__ beff)
{
    int bx = blockIdx.x, m = blockIdx.y;
    const float* Wp = m ? w_dp : w_rp;
    float* Wo = m ? W2 : W1;
    __shared__ float Wps[64][68];
    int tid = threadIdx.x;
    int sr = tid >> 4, sc4 = (tid & 15) * 4;
    #pragma unroll
    for (int rr = 0; rr < 4; ++rr) {
        int r = rr*16 + sr;
        *(float4*)&Wps[r][sc4] = *(const float4*)&Wp[r*64 + sc4];
    }
    __syncthreads();
    int r = tid >> 4;            // 0..15
    int o = bx*16 + r;
    int c4 = (tid & 15) * 4;
    float a0 = 0, a1 = 0, a2 = 0, a3 = 0;
    for (int j = 0; j < 64; ++j) {
        float wc = w_comp[o*128 + m*64 + j];
        float4 wp = *(const float4*)&Wps[j][c4];
        a0 += wc*wp.x; a1 += wc*wp.y; a2 += wc*wp.z; a3 += wc*wp.w;
    }
    Wo[o*64 + c4]     = a0;
    Wo[o*64 + c4 + 1] = a1;
    Wo[o*64 + c4 + 2] = a2;
    Wo[o*64 + c4 + 3] = a3;
    if (bx == 0 && m == 0 && tid < 64) {
        float s = b_comp[tid];
        for (int j = 0; j < 64; ++j)
            s += w_comp[tid*128 + j] * b_rp[j] + w_comp[tid*128 + 64 + j] * b_dp[j];
        beff[tid] = s;
    }
}

// prep + one of {Q,K,V} GEMM per (b,strm). grid(36, 3, 4), 256 thr.
// Output layout [sb=strm*2+b][h][n][8] bf16; Q pre-scaled by 8^-0.5*log2e.
__global__ __launch_bounds__(256) void qkv_kernel(
    const float* __restrict__ rgb, const float* __restrict__ dep,
    const float* __restrict__ w_exp, const float* __restrict__ b_exp,
    const float* __restrict__ w_rq, const float* __restrict__ w_rk, const float* __restrict__ w_rv,
    const float* __restrict__ w_dq, const float* __restrict__ w_dk, const float* __restrict__ w_dv,
    bf16_t* __restrict__ Qb, bf16_t* __restrict__ Kb, bf16_t* __restrict__ Vb)
{
    int tile = blockIdx.x;           // 0..35
    int m    = blockIdx.y;           // 0=Q 1=K 2=V
    int z    = blockIdx.z;           // b*2 + strm
    int b = z >> 1, strm = z & 1;
    const float* W = strm ? (m == 0 ? w_dq : m == 1 ? w_dk : w_dv)
                          : (m == 0 ? w_rq : m == 1 ? w_rk : w_rv);
    bf16_t* O = (m == 0 ? Qb : m == 1 ? Kb : Vb) + (size_t)(strm*2 + b) * NTOK * 64;
    float scale = (m == 0) ? (0.35355339059327373f * 1.4426950408889634f) : 1.0f;

    __shared__ float Xs[64][68];
    __shared__ float Ws[64][68];
    int tid = threadIdx.x;
    {
        int r = tid & 63, c0 = tid >> 6;
        stage_x_row(&Xs[r][0], rgb, dep, w_exp, b_exp, b, tile*64 + r, strm, c0, 4);
    }
    int sr = tid >> 4, sc = (tid & 15) * 4;
    #pragma unroll
    for (int rr = 0; rr < 4; ++rr) {
        int r = rr*16 + sr;
        *(float4*)&Ws[r][sc] = *(const float4*)&W[r*64 + sc];
    }
    __syncthreads();

    int ty = tid >> 4, tx = tid & 15;
    float acc[4][4] = {};
    #pragma unroll
    for (int k = 0; k < 64; k += 4) {
        float4 xv[4], wv4[4];
        #pragma unroll
        for (int i = 0; i < 4; ++i) xv[i] = *(const float4*)&Xs[4*ty + i][k];
        #pragma unroll
        for (int j = 0; j < 4; ++j) wv4[j] = *(const float4*)&Ws[tx + 16*j][k];
        #pragma unroll
        for (int i = 0; i < 4; ++i)
            #pragma unroll
            for (int j = 0; j < 4; ++j)
                acc[i][j] += xv[i].x*wv4[j].x + xv[i].y*wv4[j].y + xv[i].z*wv4[j].z + xv[i].w*wv4[j].w;
    }
    // store into [h][n][8]
    #pragma unroll
    for (int j = 0; j < 4; ++j) {
        int o = tx + 16*j;
        int h = o >> 3, d = o & 7;
        #pragma unroll
        for (int i = 0; i < 4; ++i) {
            int n = tile*64 + 4*ty + i;
            O[((size_t)h * NTOK + n) * 8 + d] = f2bf(acc[i][j] * scale);
        }
    }
}

// Flash attention, no-max (scores bounded), R=4 queries/lane.
// grid(9, 8, 12): qt(256 q) x head x (bw*3 + ksplit). 256 thr = 4 waves.
// Wave w owns keys [ks*768 + w*192, +192) in 3 x 64-key tiles staged to its
// PRIVATE LDS quadrant — no barriers. Partials merged via global atomicAdd
// into AO[b][n][h][9] (8 acc + l), zeroed beforehand.
__global__ __launch_bounds__(256) void attn_kernel(
    const bf16_t* __restrict__ Qb, const bf16_t* __restrict__ Kb,
    const bf16_t* __restrict__ Vb,
    float* __restrict__ AOr, float* __restrict__ AOd)
{
    int qt = blockIdx.x;          // 0..8
    int h  = blockIdx.y;          // 0..7
    int z  = blockIdx.z;          // 0..11
    int bw = z / 3, ks = z % 3;
    int b = bw >> 1, which = bw & 1;
    int qsb = which * 2 + b;      // query stream-batch (which==0 -> rgb)
    int ksb = (1 - which) * 2 + b;
    const bf16_t* Q = Qb + ((size_t)qsb * 8 + h) * NTOK * 8;
    const bf16_t* K = Kb + ((size_t)ksb * 8 + h) * NTOK * 8;
    const bf16_t* V = Vb + ((size_t)ksb * 8 + h) * NTOK * 8;
    float* AO = which ? AOd : AOr;

    __shared__ __align__(16) float Ks[4][64][KVSTRIDE];
    __shared__ __align__(16) float Vs[4][64][KVSTRIDE];

    int tid = threadIdx.x;
    int t = tid & 63, w = tid >> 6;
    int n0 = qt * 256 + t;

    float q[4][8];
    #pragma unroll
    for (int j = 0; j < 4; ++j) {
        const bf16_t* qp = &Q[(size_t)(n0 + 64*j) * 8];
        float4 qa = ld_bf4(qp), qb = ld_bf4(qp + 4);
        q[j][0]=qa.x; q[j][1]=qa.y; q[j][2]=qa.z; q[j][3]=qa.w;
        q[j][4]=qb.x; q[j][5]=qb.y; q[j][6]=qb.z; q[j][7]=qb.w;
    }

    float l[4] = {0.f, 0.f, 0.f, 0.f};
    float acc[4][8] = {};

    int kbase = ks * 768 + w * 192;
    #pragma unroll 1
    for (int kt = 0; kt < 3; ++kt) {
        int key = kbase + kt*64 + t;
        const bf16_t* kp = &K[(size_t)key * 8];
        const bf16_t* vp = &V[(size_t)key * 8];
        *(float4*)&Ks[w][t][0] = ld_bf4(kp);
        *(float4*)&Ks[w][t][4] = ld_bf4(kp + 4);
        *(float4*)&Vs[w][t][0] = ld_bf4(vp);
        *(float4*)&Vs[w][t][4] = ld_bf4(vp + 4);
        // same-wave LDS RAW -> compiler lgkmcnt wait; wave-synchronous, no barrier.
        #pragma unroll 4
        for (int u = 0; u < 64; ++u) {
            float4 ka = *(const float4*)&Ks[w][u][0];
            float4 kb = *(const float4*)&Ks[w][u][4];
            float4 va = *(const float4*)&Vs[w][u][0];
            float4 vb = *(const float4*)&Vs[w][u][4];
            #pragma unroll
            for (int j = 0; j < 4; ++j) {
                float s = q[j][0]*ka.x + q[j][1]*ka.y + q[j][2]*ka.z + q[j][3]*ka.w
                        + q[j][4]*kb.x + q[j][5]*kb.y + q[j][6]*kb.z + q[j][7]*kb.w;
                float p = __builtin_amdgcn_exp2f(s);
                l[j] += p;
                acc[j][0] += p*va.x; acc[j][1] += p*va.y;
                acc[j][2] += p*va.z; acc[j][3] += p*va.w;
                acc[j][4] += p*vb.x; acc[j][5] += p*vb.y;
                acc[j][6] += p*vb.z; acc[j][7] += p*vb.w;
            }
        }
    }

    #pragma unroll
    for (int j = 0; j < 4; ++j) {
        float* dst = &AO[(((size_t)b * NTOK + (n0 + 64*j)) * 8 + h) * 9];
        #pragma unroll
        for (int d = 0; d < 8; ++d) atomicAdd(&dst[d], acc[j][d]);
        atomicAdd(&dst[8], l[j]);
    }
}

// Normalize AO (acc/l) + fused 2x K=64 GEMM (W1,W2) + beff + GELU + store.
// grid(72, 2): 32-token tiles x batch. 256 thr.
__global__ __launch_bounds__(256) void outcomp_kernel(
    const float* __restrict__ AOr, const float* __restrict__ AOd,
    const float* __restrict__ W1, const float* __restrict__ W2,
    const float* __restrict__ beff, float* __restrict__ out)
{
    int tile = blockIdx.x;       // 0..71
    int b    = blockIdx.y;
    int n0 = tile * 32;
    __shared__ float Ar[32][68];
    __shared__ float Ad[32][68];
    __shared__ float W1s[64][68];
    __shared__ float W2s[64][68];
    int tid = threadIdx.x;
    {
        int row = tid >> 3, h = tid & 7;
        const float* pr = &AOr[(((size_t)b * NTOK + (n0 + row)) * 8 + h) * 9];
        const float* pd = &AOd[(((size_t)b * NTOK + (n0 + row)) * 8 + h) * 9];
        float invr = 1.0f / pr[8];
        float invd = 1.0f / pd[8];
        #pragma unroll
        for (int d = 0; d < 8; ++d) {
            Ar[row][8*h + d] = pr[d] * invr;
            Ad[row][8*h + d] = pd[d] * invd;
        }
    }
    {
        int sr = tid >> 4, sc4 = (tid & 15) * 4;
        #pragma unroll
        for (int rr = 0; rr < 4; ++rr) {
            int r = rr*16 + sr;
            *(float4*)&W1s[r][sc4] = *(const float4*)&W1[r*64 + sc4];
            *(float4*)&W2s[r][sc4] = *(const float4*)&W2[r*64 + sc4];
        }
    }
    __syncthreads();

    int tx = tid & 15, ty = tid >> 4;   // outs tx+16jj, rows 2ty,2ty+1
    float g[2][4] = {};
    #pragma unroll
    for (int k = 0; k < 64; k += 4) {
        float4 xr0 = *(const float4*)&Ar[2*ty][k];
        float4 xr1 = *(const float4*)&Ar[2*ty + 1][k];
        float4 xd0 = *(const float4*)&Ad[2*ty][k];
        float4 xd1 = *(const float4*)&Ad[2*ty + 1][k];
        #pragma unroll
        for (int jj = 0; jj < 4; ++jj) {
            float4 w1 = *(const float4*)&W1s[tx + 16*jj][k];
            float4 w2 = *(const float4*)&W2s[tx + 16*jj][k];
            g[0][jj] += xr0.x*w1.x + xr0.y*w1.y + xr0.z*w1.z + xr0.w*w1.w
                      + xd0.x*w2.x + xd0.y*w2.y + xd0.z*w2.z + xd0.w*w2.w;
            g[1][jj] += xr1.x*w1.x + xr1.y*w1.y + xr1.z*w1.z + xr1.w*w1.w
                      + xd1.x*w2.x + xd1.y*w2.y + xd1.z*w2.z + xd1.w*w2.w;
        }
    }
    #pragma unroll
    for (int jj = 0; jj < 4; ++jj) {
        int o = tx + 16*jj;
        float be = beff[o];
        #pragma unroll
        for (int i = 0; i < 2; ++i) {
            int n = n0 + 2*ty + i;
            int wi = n / HH, hi = n % HH;
            float x = g[i][jj] + be;
            float gl = 0.5f * x * (1.0f + erff(x * 0.70710678118654752f));
            out[((b*C + o)*WW + wi)*HH + hi] = gl;
        }
    }
}

// ===========================================================================
// FALLBACK (R9 big path, proven 408us): ws >= 3,538,944 B.
// ===========================================================================
__global__ __launch_bounds__(256) void kv_all_kernel(
    const float* __restrict__ rgb, const float* __restrict__ dep,
    const float* __restrict__ w_exp, const float* __restrict__ b_exp,
    const float* __restrict__ w_rk, const float* __restrict__ w_rv,
    const float* __restrict__ w_dk, const float* __restrict__ w_dv,
    bf16_t* __restrict__ Kr, bf16_t* __restrict__ Vr,
    bf16_t* __restrict__ Kd, bf16_t* __restrict__ Vd)
{
    int tile = blockIdx.x;
    int m    = blockIdx.y;
    int z    = blockIdx.z;
    int b = z >> 1, strm = z & 1;
    const float* W = strm ? (m ? w_dv : w_dk) : (m ? w_rv : w_rk);
    bf16_t* O = (strm ? (m ? Vd : Kd) : (m ? Vr : Kr))
              + ((size_t)b * NTOK + tile * 64) * 64;

    __shared__ float Xs[64][68];
    __shared__ float Ws[64][68];
    int tid = threadIdx.x;
    {
        int r = tid & 63, c0 = tid >> 6;
        stage_x_row(&Xs[r][0], rgb, dep, w_exp, b_exp, b, tile*64 + r, strm, c0, 4);
    }
    int sr = tid >> 4, sc = (tid & 15) * 4;
    #pragma unroll
    for (int rr = 0; rr < 4; ++rr) {
        int r = rr*16 + sr;
        *(float4*)&Ws[r][sc] = *(const float4*)&W[r*64 + sc];
    }
    __syncthreads();

    int ty = tid >> 4, tx = tid & 15;
    float acc[4][4] = {};
    #pragma unroll
    for (int k = 0; k < 64; k += 4) {
        float4 xv[4], wv4[4];
        #pragma unroll
        for (int i = 0; i < 4; ++i) xv[i] = *(const float4*)&Xs[4*ty + i][k];
        #pragma unroll
        for (int j = 0; j < 4; ++j) wv4[j] = *(const float4*)&Ws[tx + 16*j][k];
        #pragma unroll
        for (int i = 0; i < 4; ++i)
            #pragma unroll
            for (int j = 0; j < 4; ++j)
                acc[i][j] += xv[i].x*wv4[j].x + xv[i].y*wv4[j].y + xv[i].z*wv4[j].z + xv[i].w*wv4[j].w;
    }
    #pragma unroll
    for (int i = 0; i < 4; ++i)
        #pragma unroll
        for (int j = 0; j < 4; ++j)
            O[(4*ty + i)*64 + tx + 16*j] = f2bf(acc[i][j]);
}

__global__ __launch_bounds__(256) void attn_all_kernel(
    const float* __restrict__ rgb, const float* __restrict__ dep,
    const float* __restrict__ w_exp, const float* __restrict__ b_exp,
    const float* __restrict__ w_rq, const float* __restrict__ w_dq,
    const bf16_t* __restrict__ Kr, const bf16_t* __restrict__ Vr,
    const bf16_t* __restrict__ Kd, const bf16_t* __restrict__ Vd,
    bf16_t* __restrict__ AOr, bf16_t* __restrict__ AOd)
{
    int qt = blockIdx.x;
    int h  = blockIdx.y;
    int z  = blockIdx.z;
    int b = z >> 1, which = z & 1;
    const float* wq = which ? w_dq : w_rq;
    const bf16_t* K = which ? Kr : Kd;
    const bf16_t* V = which ? Vr : Vd;
    bf16_t* AO      = which ? AOd : AOr;

    __shared__ float Xs[64][68];
    __shared__ float Wqs[8][64];
    __shared__ __align__(16) float Ks[4][64][KVSTRIDE];
    __shared__ __align__(16) float Vs[4][64][KVSTRIDE];

    int tid = threadIdx.x;
    int t = tid & 63;
    int w = tid >> 6;
    int n = qt * 64 + t;

    stage_x_row(&Xs[t][0], rgb, dep, w_exp, b_exp, b, n, which == 0 ? 0 : 1, w, 4);
    if (w == 0) {
        #pragma unroll
        for (int d = 0; d < 8; ++d) Wqs[d][t] = wq[(8*h + d)*64 + t];
    }
    __syncthreads();

    const float sc = 0.35355339059327373f * 1.4426950408889634f;
    float q[8];
    #pragma unroll
    for (int d = 0; d < 8; ++d) {
        float s = 0.f;
        #pragma unroll 8
        for (int c = 0; c < 64; ++c) s += Xs[t][c] * Wqs[d][c];
        q[d] = s * sc;
    }

    float mrun = -INFINITY, l = 0.f;
    float acc[8] = {};

    #pragma unroll 1
    for (int st = 0; st < 9; ++st) {
        __syncthreads();
        {
            size_t g = ((size_t)b * NTOK + (w*576 + st*64 + t)) * 64 + 8 * h;
            *(float4*)&Ks[w][t][0] = ld_bf4(&K[g]);
            *(float4*)&Ks[w][t][4] = ld_bf4(&K[g + 4]);
            *(float4*)&Vs[w][t][0] = ld_bf4(&V[g]);
            *(float4*)&Vs[w][t][4] = ld_bf4(&V[g + 4]);
        }
        __syncthreads();

        for (int g8 = 0; g8 < 8; ++g8) {
            float s[8];
            #pragma unroll
            for (int u = 0; u < 8; ++u) {
                const float4 ka = *(const float4*)&Ks[w][g8*8 + u][0];
                const float4 kb = *(const float4*)&Ks[w][g8*8 + u][4];
                s[u] = q[0]*ka.x + q[1]*ka.y + q[2]*ka.z + q[3]*ka.w
                     + q[4]*kb.x + q[5]*kb.y + q[6]*kb.z + q[7]*kb.w;
            }
            float tm = fmaxf(fmaxf(fmaxf(s[0],s[1]), fmaxf(s[2],s[3])),
                             fmaxf(fmaxf(s[4],s[5]), fmaxf(s[6],s[7])));
            float mn = fmaxf(mrun, tm);
            float alpha = __builtin_amdgcn_exp2f(mrun - mn);
            float ps = 0.f;
            #pragma unroll
            for (int u = 0; u < 8; ++u) { s[u] = __builtin_amdgcn_exp2f(s[u] - mn); ps += s[u]; }
            l = l * alpha + ps;
            #pragma unroll
            for (int d = 0; d < 8; ++d) acc[d] *= alpha;
            #pragma unroll
            for (int u = 0; u < 8; ++u) {
                const float4 va = *(const float4*)&Vs[w][g8*8 + u][0];
                const float4 vb = *(const float4*)&Vs[w][g8*8 + u][4];
                acc[0] += s[u]*va.x; acc[1] += s[u]*va.y; acc[2] += s[u]*va.z; acc[3] += s[u]*va.w;
                acc[4] += s[u]*vb.x; acc[5] += s[u]*vb.y; acc[6] += s[u]*vb.z; acc[7] += s[u]*vb.w;
            }
            mrun = mn;
        }
    }

    float* part = &Xs[0][0];
    __syncthreads();
    {
        float* p = &part[(w*64 + t) * 10];
        p[0] = mrun; p[1] = l;
        #pragma unroll
        for (int d = 0; d < 8; ++d) p[2 + d] = acc[d];
    }
    __syncthreads();
    if (tid < 64) {
        float M = -INFINITY;
        #pragma unroll
        for (int v = 0; v < 4; ++v) M = fmaxf(M, part[(v*64 + t)*10]);
        float L = 0.f, o[8] = {};
        #pragma unroll
        for (int v = 0; v < 4; ++v) {
            const float* p = &part[(v*64 + t)*10];
            float al = __builtin_amdgcn_exp2f(p[0] - M);
            L += p[1] * al;
            #pragma unroll
            for (int d = 0; d < 8; ++d) o[d] += p[2 + d] * al;
        }
        float inv = 1.0f / L;
        uint4 ov;
        ov.x = pack2(o[0]*inv, o[1]*inv);
        ov.y = pack2(o[2]*inv, o[3]*inv);
        ov.z = pack2(o[4]*inv, o[5]*inv);
        ov.w = pack2(o[6]*inv, o[7]*inv);
        *(uint4*)&AO[((size_t)b * NTOK + n) * 64 + 8 * h] = ov;
    }
}

__global__ __launch_bounds__(256) void projcomp_all_kernel(
    const bf16_t* __restrict__ AOr, const bf16_t* __restrict__ AOd,
    const float* __restrict__ w_rp, const float* __restrict__ b_rp,
    const float* __restrict__ w_dp, const float* __restrict__ b_dp,
    const float* __restrict__ w_comp, const float* __restrict__ b_comp,
    float* __restrict__ out)
{
    int tile = blockIdx.x;
    int b    = blockIdx.y;
    __shared__ float A[64][68];
    __shared__ float Bf[64][68];
    __shared__ float Pf[64][68];
    int tid = threadIdx.x;
    int sr = tid >> 4, sc = (tid & 15) * 4;
    int ty = tid >> 4, tx = tid & 15;
    float G[4][4] = {};

    #pragma unroll
    for (int half = 0; half < 2; ++half) {
        const bf16_t* AOx = half ? AOd : AOr;
        const float* Wp   = half ? w_dp : w_rp;
        const float* bp   = half ? b_dp : b_rp;
        #pragma unroll
        for (int rr = 0; rr < 4; ++rr) {
            int r = rr*16 + sr;
            *(float4*)&A[r][sc]  = ld_bf4(&AOx[((size_t)b*NTOK + tile*64 + r)*64 + sc]);
            *(float4*)&Bf[r][sc] = *(const float4*)&Wp[r*64 + sc];
        }
        __syncthreads();
        float acc[4][4] = {};
        #pragma unroll
        for (int k = 0; k < 64; k += 4) {
            float4 xv[4], wv[4];
            #pragma unroll
            for (int i = 0; i < 4; ++i) xv[i] = *(const float4*)&A[4*ty + i][k];
            #pragma unroll
            for (int j = 0; j < 4; ++j) wv[j] = *(const float4*)&Bf[tx + 16*j][k];
            #pragma unroll
            for (int i = 0; i < 4; ++i)
                #pragma unroll
                for (int j = 0; j < 4; ++j)
                    acc[i][j] += xv[i].x*wv[j].x + xv[i].y*wv[j].y + xv[i].z*wv[j].z + xv[i].w*wv[j].w;
        }
        __syncthreads();
        #pragma unroll
        for (int j = 0; j < 4; ++j) {
            float bj = bp[tx + 16*j];
            #pragma unroll
            for (int i = 0; i < 4; ++i)
                Pf[4*ty + i][tx + 16*j] = acc[i][j] + bj;
        }
        #pragma unroll
        for (int rr = 0; rr < 4; ++rr) {
            int r = rr*16 + sr;
            *(float4*)&Bf[r][sc] = *(const float4*)&w_comp[r*128 + half*64 + sc];
        }
        __syncthreads();
        #pragma unroll
        for (int k = 0; k < 64; k += 4) {
            float4 xv[4], wv[4];
            #pragma unroll
            for (int i = 0; i < 4; ++i) xv[i] = *(const float4*)&Pf[4*ty + i][k];
            #pragma unroll
            for (int j = 0; j < 4; ++j) wv[j] = *(const float4*)&Bf[tx + 16*j][k];
            #pragma unroll
            for (int i = 0; i < 4; ++i)
                #pragma unroll
                for (int j = 0; j < 4; ++j)
                    G[i][j] += xv[i].x*wv[j].x + xv[i].y*wv[j].y + xv[i].z*wv[j].z + xv[i].w*wv[j].w;
        }
        __syncthreads();
    }

    #pragma unroll
    for (int j = 0; j < 4; ++j) {
        int o = tx + 16*j;
        float bj = b_comp[o];
        #pragma unroll
        for (int i = 0; i < 4; ++i) {
            int n = tile*64 + 4*ty + i;
            int wi = n / HH, hi = n % HH;
            float x = G[i][j] + bj;
            float g = 0.5f * x * (1.0f + erff(x * 0.70710678118654752f));
            out[((b*C + o)*WW + wi)*HH + hi] = g;
        }
    }
}

// ---------------------------------------------------------------------------
extern "C" void kernel_launch(void* const* d_in, const int* in_sizes, int n_in,
                              void* d_out, int out_size, void* d_ws, size_t ws_size,
                              hipStream_t stream) {
    const float* rgb_fea = (const float*)d_in[0];
    const float* depth   = (const float*)d_in[1];
    const float* w_exp   = (const float*)d_in[2];
    const float* b_exp   = (const float*)d_in[3];
    const float* w_rq    = (const float*)d_in[4];
    const float* w_rk    = (const float*)d_in[5];
    const float* w_rv    = (const float*)d_in[6];
    const float* w_dq    = (const float*)d_in[7];
    const float* w_dk    = (const float*)d_in[8];
    const float* w_dv    = (const float*)d_in[9];
    const float* w_rp    = (const float*)d_in[10];
    const float* b_rp    = (const float*)d_in[11];
    const float* w_dp    = (const float*)d_in[12];
    const float* b_dp    = (const float*)d_in[13];
    const float* w_comp  = (const float*)d_in[14];
    const float* b_comp  = (const float*)d_in[15];
    float* out = (float*)d_out;

    if (ws_size >= 6226176) {
        char* Wb = (char*)d_ws;
        bf16_t* Qb  = (bf16_t*)Wb;
        bf16_t* Kb  = (bf16_t*)(Wb + 1179648);
        bf16_t* Vb  = (bf16_t*)(Wb + 2359296);
        float* AOr  = (float*)(Wb + 3538944);   // [2][2304][8][9] fp32
        float* AOd  = (float*)(Wb + 4866048);
        float* W1   = (float*)(Wb + 6193152);
        float* W2   = (float*)(Wb + 6209536);
        float* beff = (float*)(Wb + 6225920);

        zero_kernel<<<dim3(648), dim3(256), 0, stream>>>((float4*)AOr, 165888);
        wprep_kernel<<<dim3(4, 2), dim3(256), 0, stream>>>(
            w_rp, w_dp, w_comp, b_rp, b_dp, b_comp, W1, W2, beff);
        qkv_kernel<<<dim3(36, 3, 4), dim3(256), 0, stream>>>(
            rgb_fea, depth, w_exp, b_exp,
            w_rq, w_rk, w_rv, w_dq, w_dk, w_dv, Qb, Kb, Vb);
        attn_kernel<<<dim3(9, 8, 12), dim3(256), 0, stream>>>(
            Qb, Kb, Vb, AOr, AOd);
        outcomp_kernel<<<dim3(72, 2), dim3(256), 0, stream>>>(
            AOr, AOd, W1, W2, beff, out);
    } else {
        // R9 big path (proven)
        const size_t BUF = (size_t)BATCH * NTOK * 64;
        bf16_t* Kr  = (bf16_t*)d_ws;
        bf16_t* Vr  = Kr + BUF;
        bf16_t* Kd  = Vr + BUF;
        bf16_t* Vd  = Kd + BUF;
        bf16_t* AOr = Vd + BUF;
        bf16_t* AOd = AOr + BUF;
        kv_all_kernel<<<dim3(36, 2, 4), dim3(256), 0, stream>>>(
            rgb_fea, depth, w_exp, b_exp, w_rk, w_rv, w_dk, w_dv, Kr, Vr, Kd, Vd);
        attn_all_kernel<<<dim3(36, 8, 4), dim3(256), 0, stream>>>(
            rgb_fea, depth, w_exp, b_exp, w_rq, w_dq, Kr, Vr, Kd, Vd, AOr, AOd);
        projcomp_all_kernel<<<dim3(36, 2), dim3(256), 0, stream>>>(
            AOr, AOd, w_rp, b_rp, w_dp, b_dp, w_comp, b_comp, out);
    }
}

// Round 11
// 324.241 us; speedup vs baseline: 1.7837x; 1.7837x over previous
//
#include <hip/hip_runtime.h>
#include <math.h>

// R10: 578us. attn 452us — atomicAdd merge wrote 255MB to HBM (WRITE_SIZE
// 248832KB), VALUBusy 17.6%. R11: in-block LDS merge (plain sum — no-max
// softmax makes it exact), no atomics; bf16 K/V in LDS (2 ds_read_b128/key
// instead of 4); AO stored normalized fp32; zero_kernel removed.
#define BATCH 2
#define C 64
#define HH 48
#define WW 48
#define NTOK 2304
#define HEADS 8
#define KVSTRIDE 12

typedef unsigned short bf16_t;
__device__ __forceinline__ bf16_t f2bf(float f) {
    unsigned int u = __float_as_uint(f);
    u = (u + 0x7fffu + ((u >> 16) & 1u)) >> 16;   // RNE
    return (bf16_t)u;
}
__device__ __forceinline__ unsigned pack2(float a, float b) {
    return (unsigned)f2bf(a) | ((unsigned)f2bf(b) << 16);
}
__device__ __forceinline__ float4 ld_bf4(const bf16_t* p) {
    uint2 v = *(const uint2*)p;
    float4 r;
    r.x = __uint_as_float(v.x << 16); r.y = __uint_as_float(v.x & 0xffff0000u);
    r.z = __uint_as_float(v.y << 16); r.w = __uint_as_float(v.y & 0xffff0000u);
    return r;
}
__device__ __forceinline__ void bf8_unpack(uint4 v, float* o) {
    o[0] = __uint_as_float(v.x << 16); o[1] = __uint_as_float(v.x & 0xffff0000u);
    o[2] = __uint_as_float(v.y << 16); o[3] = __uint_as_float(v.y & 0xffff0000u);
    o[4] = __uint_as_float(v.z << 16); o[5] = __uint_as_float(v.z & 0xffff0000u);
    o[6] = __uint_as_float(v.w << 16); o[7] = __uint_as_float(v.w & 0xffff0000u);
}

// Stage one token-row of X. strm 0: rgb transpose gather. strm 1: conv1x1+
// ReLU+bilinear x2 (half-pixel; clamp == jax edge renorm for 24->48).
__device__ __forceinline__ void stage_x_row(
    float* xrow, const float* rgb, const float* dep,
    const float* w_exp, const float* b_exp,
    int b, int n, int strm, int c0, int cstep)
{
    int wi = n / HH, hi = n % HH;
    if (strm == 0) {
        const float* base = rgb + (size_t)b * C * NTOK + (size_t)hi * WW + wi;
        for (int c = c0; c < 64; c += cstep)
            xrow[c] = base[(size_t)c * NTOK];
    } else {
        float cy = 0.5f * hi - 0.25f, cx = 0.5f * wi - 0.25f;
        float fy0 = floorf(cy), fx0 = floorf(cx);
        float fy = cy - fy0, fx = cx - fx0;
        int y0 = max((int)fy0, 0), x0 = max((int)fx0, 0);
        int y1 = min((int)fy0 + 1, 23), x1 = min((int)fx0 + 1, 23);
        const float* dp = dep + b * 576;
        float d00 = dp[y0*24 + x0], d01 = dp[y0*24 + x1];
        float d10 = dp[y1*24 + x0], d11 = dp[y1*24 + x1];
        for (int c = c0; c < 64; c += cstep) {
            float w = w_exp[c], bb = b_exp[c];
            float r00 = fmaxf(w*d00 + bb, 0.f), r01 = fmaxf(w*d01 + bb, 0.f);
            float r10 = fmaxf(w*d10 + bb, 0.f), r11 = fmaxf(w*d11 + bb, 0.f);
            xrow[c] = (1.f-fy)*((1.f-fx)*r00 + fx*r01) + fy*((1.f-fx)*r10 + fx*r11);
        }
    }
}

// ===========================================================================
// MAIN PATH (ws >= 5,931,264 B)
// ===========================================================================

// W1 = Wc[:, :64] @ Wrp ; W2 = Wc[:, 64:] @ Wdp ; beff = Wc@[br;bd] + bc.
__global__ __launch_bounds__(256) void wprep_kernel(
    const float* __restrict__ w_rp, const float* __restrict__ w_dp,
    const float* __restrict__ w_comp,
    const float* __restrict__ b_rp, const float* __restrict__ b_dp,
    const float* __restrict__ b_comp,
    float* __restrict__ W1, float* __restrict__ W2, float* __restrict__ beff)
{
    int bx = blockIdx.x, m = blockIdx.y;
    const float* Wp = m ? w_dp : w_rp;
    float* Wo = m ? W2 : W1;
    __shared__ float Wps[64][68];
    int tid = threadIdx.x;
    int sr = tid >> 4, sc4 = (tid & 15) * 4;
    #pragma unroll
    for (int rr = 0; rr < 4; ++rr) {
        int r = rr*16 + sr;
        *(float4*)&Wps[r][sc4] = *(const float4*)&Wp[r*64 + sc4];
    }
    __syncthreads();
    int r = tid >> 4;
    int o = bx*16 + r;
    int c4 = (tid & 15) * 4;
    float a0 = 0, a1 = 0, a2 = 0, a3 = 0;
    for (int j = 0; j < 64; ++j) {
        float wc = w_comp[o*128 + m*64 + j];
        float4 wp = *(const float4*)&Wps[j][c4];
        a0 += wc*wp.x; a1 += wc*wp.y; a2 += wc*wp.z; a3 += wc*wp.w;
    }
    Wo[o*64 + c4]     = a0;
    Wo[o*64 + c4 + 1] = a1;
    Wo[o*64 + c4 + 2] = a2;
    Wo[o*64 + c4 + 3] = a3;
    if (bx == 0 && m == 0 && tid < 64) {
        float s = b_comp[tid];
        for (int j = 0; j < 64; ++j)
            s += w_comp[tid*128 + j] * b_rp[j] + w_comp[tid*128 + 64 + j] * b_dp[j];
        beff[tid] = s;
    }
}

// prep + one of {Q,K,V} GEMM per (b,strm). grid(36, 3, 4), 256 thr.
// Output [sb=strm*2+b][h][n][8] bf16; Q pre-scaled by 8^-0.5*log2e.
__global__ __launch_bounds__(256) void qkv_kernel(
    const float* __restrict__ rgb, const float* __restrict__ dep,
    const float* __restrict__ w_exp, const float* __restrict__ b_exp,
    const float* __restrict__ w_rq, const float* __restrict__ w_rk, const float* __restrict__ w_rv,
    const float* __restrict__ w_dq, const float* __restrict__ w_dk, const float* __restrict__ w_dv,
    bf16_t* __restrict__ Qb, bf16_t* __restrict__ Kb, bf16_t* __restrict__ Vb)
{
    int tile = blockIdx.x;
    int m    = blockIdx.y;
    int z    = blockIdx.z;
    int b = z >> 1, strm = z & 1;
    const float* W = strm ? (m == 0 ? w_dq : m == 1 ? w_dk : w_dv)
                          : (m == 0 ? w_rq : m == 1 ? w_rk : w_rv);
    bf16_t* O = (m == 0 ? Qb : m == 1 ? Kb : Vb) + (size_t)(strm*2 + b) * NTOK * 64;
    float scale = (m == 0) ? (0.35355339059327373f * 1.4426950408889634f) : 1.0f;

    __shared__ float Xs[64][68];
    __shared__ float Ws[64][68];
    int tid = threadIdx.x;
    {
        int r = tid & 63, c0 = tid >> 6;
        stage_x_row(&Xs[r][0], rgb, dep, w_exp, b_exp, b, tile*64 + r, strm, c0, 4);
    }
    int sr = tid >> 4, sc = (tid & 15) * 4;
    #pragma unroll
    for (int rr = 0; rr < 4; ++rr) {
        int r = rr*16 + sr;
        *(float4*)&Ws[r][sc] = *(const float4*)&W[r*64 + sc];
    }
    __syncthreads();

    int ty = tid >> 4, tx = tid & 15;
    float acc[4][4] = {};
    #pragma unroll
    for (int k = 0; k < 64; k += 4) {
        float4 xv[4], wv4[4];
        #pragma unroll
        for (int i = 0; i < 4; ++i) xv[i] = *(const float4*)&Xs[4*ty + i][k];
        #pragma unroll
        for (int j = 0; j < 4; ++j) wv4[j] = *(const float4*)&Ws[tx + 16*j][k];
        #pragma unroll
        for (int i = 0; i < 4; ++i)
            #pragma unroll
            for (int j = 0; j < 4; ++j)
                acc[i][j] += xv[i].x*wv4[j].x + xv[i].y*wv4[j].y + xv[i].z*wv4[j].z + xv[i].w*wv4[j].w;
    }
    #pragma unroll
    for (int j = 0; j < 4; ++j) {
        int o = tx + 16*j;
        int h = o >> 3, d = o & 7;
        #pragma unroll
        for (int i = 0; i < 4; ++i) {
            int n = tile*64 + 4*ty + i;
            O[((size_t)h * NTOK + n) * 8 + d] = f2bf(acc[i][j] * scale);
        }
    }
}

// Flash attention: no-max softmax, R=4 queries/lane, in-block key split.
// grid(9, 8, 4): qt(256 q) x head x (b*2+which). 256 thr = 4 waves.
// Wave w owns keys [576w, 576w+576) in 9 x 64-key tiles, staged as bf16
// uint4 rows in its PRIVATE LDS quadrant (no barriers in the loop).
// Merge = plain sum over the 4 wave partials (exact for no-max softmax),
// normalized and stored fp32 to AO[b][n][64].
__global__ __launch_bounds__(256) void attn_kernel(
    const bf16_t* __restrict__ Qb, const bf16_t* __restrict__ Kb,
    const bf16_t* __restrict__ Vb,
    float* __restrict__ AOr, float* __restrict__ AOd)
{
    int qt = blockIdx.x;          // 0..8
    int h  = blockIdx.y;          // 0..7
    int z  = blockIdx.z;          // b*2 + which
    int b = z >> 1, which = z & 1;
    int qsb = which * 2 + b;
    int ksb = (1 - which) * 2 + b;
    const bf16_t* Q = Qb + ((size_t)qsb * 8 + h) * NTOK * 8;
    const bf16_t* K = Kb + ((size_t)ksb * 8 + h) * NTOK * 8;
    const bf16_t* V = Vb + ((size_t)ksb * 8 + h) * NTOK * 8;
    float* AO = which ? AOd : AOr;

    __shared__ uint4 KsB[4][64];      // [wave][key] 8 x bf16 K  (4 KB)
    __shared__ uint4 VsB[4][64];      //                      V  (4 KB)
    __shared__ float Pm[4][256][9];   // merge partials (36 KB)

    int tid = threadIdx.x;
    int t = tid & 63, w = tid >> 6;
    int n0 = qt * 256;

    float q[4][8];
    #pragma unroll
    for (int j = 0; j < 4; ++j)
        bf8_unpack(*(const uint4*)&Q[(size_t)(n0 + 64*j + t) * 8], q[j]);

    float l[4] = {0.f, 0.f, 0.f, 0.f};
    float acc[4][8] = {};

    #pragma unroll 1
    for (int kt = 0; kt < 9; ++kt) {
        int key = w*576 + kt*64 + t;
        KsB[w][t] = *(const uint4*)&K[(size_t)key * 8];
        VsB[w][t] = *(const uint4*)&V[(size_t)key * 8];
        // wave-synchronous: compiler lgkmcnt waits order write->read; no barrier.
        #pragma unroll 2
        for (int u = 0; u < 64; ++u) {
            float kf[8], vf[8];
            bf8_unpack(KsB[w][u], kf);
            bf8_unpack(VsB[w][u], vf);
            #pragma unroll
            for (int j = 0; j < 4; ++j) {
                float s = q[j][0]*kf[0] + q[j][1]*kf[1] + q[j][2]*kf[2] + q[j][3]*kf[3]
                        + q[j][4]*kf[4] + q[j][5]*kf[5] + q[j][6]*kf[6] + q[j][7]*kf[7];
                float p = __builtin_amdgcn_exp2f(s);
                l[j] += p;
                #pragma unroll
                for (int d = 0; d < 8; ++d) acc[j][d] += p * vf[d];
            }
        }
    }

    // in-block merge: plain sum over waves (exact; no-max partials are sums)
    __syncthreads();
    #pragma unroll
    for (int j = 0; j < 4; ++j) {
        float* p = &Pm[w][j*64 + t][0];
        #pragma unroll
        for (int d = 0; d < 8; ++d) p[d] = acc[j][d];
        p[8] = l[j];
    }
    __syncthreads();
    {
        int i = tid;              // query index within tile, 0..255
        float L = 0.f, o[8] = {};
        #pragma unroll
        for (int v = 0; v < 4; ++v) {
            const float* p = &Pm[v][i][0];
            #pragma unroll
            for (int d = 0; d < 8; ++d) o[d] += p[d];
            L += p[8];
        }
        float inv = 1.0f / L;
        float* dst = &AO[((size_t)b * NTOK + n0 + i) * 64 + 8 * h];
        *(float4*)&dst[0] = make_float4(o[0]*inv, o[1]*inv, o[2]*inv, o[3]*inv);
        *(float4*)&dst[4] = make_float4(o[4]*inv, o[5]*inv, o[6]*inv, o[7]*inv);
    }
}

// Fused 2x K=64 GEMM (W1,W2) + beff + GELU + transposed store.
// grid(72, 2): 32-token tiles x batch. AO rows already normalized fp32.
__global__ __launch_bounds__(256) void outcomp_kernel(
    const float* __restrict__ AOr, const float* __restrict__ AOd,
    const float* __restrict__ W1, const float* __restrict__ W2,
    const float* __restrict__ beff, float* __restrict__ out)
{
    int tile = blockIdx.x;       // 0..71
    int b    = blockIdx.y;
    int n0 = tile * 32;
    __shared__ float Ar[32][68];
    __shared__ float Ad[32][68];
    __shared__ float W1s[64][68];
    __shared__ float W2s[64][68];
    int tid = threadIdx.x;
    #pragma unroll
    for (int pass = 0; pass < 2; ++pass) {
        int idx = tid + pass*256;           // 0..511: row=idx>>4, c4=(idx&15)*4
        int row = idx >> 4, c4 = (idx & 15) * 4;
        *(float4*)&Ar[row][c4] = *(const float4*)&AOr[((size_t)b*NTOK + n0 + row)*64 + c4];
        *(float4*)&Ad[row][c4] = *(const float4*)&AOd[((size_t)b*NTOK + n0 + row)*64 + c4];
    }
    {
        int sr = tid >> 4, sc4 = (tid & 15) * 4;
        #pragma unroll
        for (int rr = 0; rr < 4; ++rr) {
            int r = rr*16 + sr;
            *(float4*)&W1s[r][sc4] = *(const float4*)&W1[r*64 + sc4];
            *(float4*)&W2s[r][sc4] = *(const float4*)&W2[r*64 + sc4];
        }
    }
    __syncthreads();

    int tx = tid & 15, ty = tid >> 4;
    float g[2][4] = {};
    #pragma unroll
    for (int k = 0; k < 64; k += 4) {
        float4 xr0 = *(const float4*)&Ar[2*ty][k];
        float4 xr1 = *(const float4*)&Ar[2*ty + 1][k];
        float4 xd0 = *(const float4*)&Ad[2*ty][k];
        float4 xd1 = *(const float4*)&Ad[2*ty + 1][k];
        #pragma unroll
        for (int jj = 0; jj < 4; ++jj) {
            float4 w1 = *(const float4*)&W1s[tx + 16*jj][k];
            float4 w2 = *(const float4*)&W2s[tx + 16*jj][k];
            g[0][jj] += xr0.x*w1.x + xr0.y*w1.y + xr0.z*w1.z + xr0.w*w1.w
                      + xd0.x*w2.x + xd0.y*w2.y + xd0.z*w2.z + xd0.w*w2.w;
            g[1][jj] += xr1.x*w1.x + xr1.y*w1.y + xr1.z*w1.z + xr1.w*w1.w
                      + xd1.x*w2.x + xd1.y*w2.y + xd1.z*w2.z + xd1.w*w2.w;
        }
    }
    #pragma unroll
    for (int jj = 0; jj < 4; ++jj) {
        int o = tx + 16*jj;
        float be = beff[o];
        #pragma unroll
        for (int i = 0; i < 2; ++i) {
            int n = n0 + 2*ty + i;
            int wi = n / HH, hi = n % HH;
            float x = g[i][jj] + be;
            float gl = 0.5f * x * (1.0f + erff(x * 0.70710678118654752f));
            out[((b*C + o)*WW + wi)*HH + hi] = gl;
        }
    }
}

// ===========================================================================
// FALLBACK (R9 big path, proven 408us): ws >= 3,538,944 B.
// ===========================================================================
__global__ __launch_bounds__(256) void kv_all_kernel(
    const float* __restrict__ rgb, const float* __restrict__ dep,
    const float* __restrict__ w_exp, const float* __restrict__ b_exp,
    const float* __restrict__ w_rk, const float* __restrict__ w_rv,
    const float* __restrict__ w_dk, const float* __restrict__ w_dv,
    bf16_t* __restrict__ Kr, bf16_t* __restrict__ Vr,
    bf16_t* __restrict__ Kd, bf16_t* __restrict__ Vd)
{
    int tile = blockIdx.x;
    int m    = blockIdx.y;
    int z    = blockIdx.z;
    int b = z >> 1, strm = z & 1;
    const float* W = strm ? (m ? w_dv : w_dk) : (m ? w_rv : w_rk);
    bf16_t* O = (strm ? (m ? Vd : Kd) : (m ? Vr : Kr))
              + ((size_t)b * NTOK + tile * 64) * 64;

    __shared__ float Xs[64][68];
    __shared__ float Ws[64][68];
    int tid = threadIdx.x;
    {
        int r = tid & 63, c0 = tid >> 6;
        stage_x_row(&Xs[r][0], rgb, dep, w_exp, b_exp, b, tile*64 + r, strm, c0, 4);
    }
    int sr = tid >> 4, sc = (tid & 15) * 4;
    #pragma unroll
    for (int rr = 0; rr < 4; ++rr) {
        int r = rr*16 + sr;
        *(float4*)&Ws[r][sc] = *(const float4*)&W[r*64 + sc];
    }
    __syncthreads();

    int ty = tid >> 4, tx = tid & 15;
    float acc[4][4] = {};
    #pragma unroll
    for (int k = 0; k < 64; k += 4) {
        float4 xv[4], wv4[4];
        #pragma unroll
        for (int i = 0; i < 4; ++i) xv[i] = *(const float4*)&Xs[4*ty + i][k];
        #pragma unroll
        for (int j = 0; j < 4; ++j) wv4[j] = *(const float4*)&Ws[tx + 16*j][k];
        #pragma unroll
        for (int i = 0; i < 4; ++i)
            #pragma unroll
            for (int j = 0; j < 4; ++j)
                acc[i][j] += xv[i].x*wv4[j].x + xv[i].y*wv4[j].y + xv[i].z*wv4[j].z + xv[i].w*wv4[j].w;
    }
    #pragma unroll
    for (int i = 0; i < 4; ++i)
        #pragma unroll
        for (int j = 0; j < 4; ++j)
            O[(4*ty + i)*64 + tx + 16*j] = f2bf(acc[i][j]);
}

__global__ __launch_bounds__(256) void attn_all_kernel(
    const float* __restrict__ rgb, const float* __restrict__ dep,
    const float* __restrict__ w_exp, const float* __restrict__ b_exp,
    const float* __restrict__ w_rq, const float* __restrict__ w_dq,
    const bf16_t* __restrict__ Kr, const bf16_t* __restrict__ Vr,
    const bf16_t* __restrict__ Kd, const bf16_t* __restrict__ Vd,
    bf16_t* __restrict__ AOr, bf16_t* __restrict__ AOd)
{
    int qt = blockIdx.x;
    int h  = blockIdx.y;
    int z  = blockIdx.z;
    int b = z >> 1, which = z & 1;
    const float* wq = which ? w_dq : w_rq;
    const bf16_t* K = which ? Kr : Kd;
    const bf16_t* V = which ? Vr : Vd;
    bf16_t* AO      = which ? AOd : AOr;

    __shared__ float Xs[64][68];
    __shared__ float Wqs[8][64];
    __shared__ __align__(16) float Ks[4][64][KVSTRIDE];
    __shared__ __align__(16) float Vs[4][64][KVSTRIDE];

    int tid = threadIdx.x;
    int t = tid & 63;
    int w = tid >> 6;
    int n = qt * 64 + t;

    stage_x_row(&Xs[t][0], rgb, dep, w_exp, b_exp, b, n, which == 0 ? 0 : 1, w, 4);
    if (w == 0) {
        #pragma unroll
        for (int d = 0; d < 8; ++d) Wqs[d][t] = wq[(8*h + d)*64 + t];
    }
    __syncthreads();

    const float sc = 0.35355339059327373f * 1.4426950408889634f;
    float q[8];
    #pragma unroll
    for (int d = 0; d < 8; ++d) {
        float s = 0.f;
        #pragma unroll 8
        for (int c = 0; c < 64; ++c) s += Xs[t][c] * Wqs[d][c];
        q[d] = s * sc;
    }

    float mrun = -INFINITY, l = 0.f;
    float acc[8] = {};

    #pragma unroll 1
    for (int st = 0; st < 9; ++st) {
        __syncthreads();
        {
            size_t g = ((size_t)b * NTOK + (w*576 + st*64 + t)) * 64 + 8 * h;
            *(float4*)&Ks[w][t][0] = ld_bf4(&K[g]);
            *(float4*)&Ks[w][t][4] = ld_bf4(&K[g + 4]);
            *(float4*)&Vs[w][t][0] = ld_bf4(&V[g]);
            *(float4*)&Vs[w][t][4] = ld_bf4(&V[g + 4]);
        }
        __syncthreads();

        for (int g8 = 0; g8 < 8; ++g8) {
            float s[8];
            #pragma unroll
            for (int u = 0; u < 8; ++u) {
                const float4 ka = *(const float4*)&Ks[w][g8*8 + u][0];
                const float4 kb = *(const float4*)&Ks[w][g8*8 + u][4];
                s[u] = q[0]*ka.x + q[1]*ka.y + q[2]*ka.z + q[3]*ka.w
                     + q[4]*kb.x + q[5]*kb.y + q[6]*kb.z + q[7]*kb.w;
            }
            float tm = fmaxf(fmaxf(fmaxf(s[0],s[1]), fmaxf(s[2],s[3])),
                             fmaxf(fmaxf(s[4],s[5]), fmaxf(s[6],s[7])));
            float mn = fmaxf(mrun, tm);
            float alpha = __builtin_amdgcn_exp2f(mrun - mn);
            float ps = 0.f;
            #pragma unroll
            for (int u = 0; u < 8; ++u) { s[u] = __builtin_amdgcn_exp2f(s[u] - mn); ps += s[u]; }
            l = l * alpha + ps;
            #pragma unroll
            for (int d = 0; d < 8; ++d) acc[d] *= alpha;
            #pragma unroll
            for (int u = 0; u < 8; ++u) {
                const float4 va = *(const float4*)&Vs[w][g8*8 + u][0];
                const float4 vb = *(const float4*)&Vs[w][g8*8 + u][4];
                acc[0] += s[u]*va.x; acc[1] += s[u]*va.y; acc[2] += s[u]*va.z; acc[3] += s[u]*va.w;
                acc[4] += s[u]*vb.x; acc[5] += s[u]*vb.y; acc[6] += s[u]*vb.z; acc[7] += s[u]*vb.w;
            }
            mrun = mn;
        }
    }

    float* part = &Xs[0][0];
    __syncthreads();
    {
        float* p = &part[(w*64 + t) * 10];
        p[0] = mrun; p[1] = l;
        #pragma unroll
        for (int d = 0; d < 8; ++d) p[2 + d] = acc[d];
    }
    __syncthreads();
    if (tid < 64) {
        float M = -INFINITY;
        #pragma unroll
        for (int v = 0; v < 4; ++v) M = fmaxf(M, part[(v*64 + t)*10]);
        float L = 0.f, o[8] = {};
        #pragma unroll
        for (int v = 0; v < 4; ++v) {
            const float* p = &part[(v*64 + t)*10];
            float al = __builtin_amdgcn_exp2f(p[0] - M);
            L += p[1] * al;
            #pragma unroll
            for (int d = 0; d < 8; ++d) o[d] += p[2 + d] * al;
        }
        float inv = 1.0f / L;
        uint4 ov;
        ov.x = pack2(o[0]*inv, o[1]*inv);
        ov.y = pack2(o[2]*inv, o[3]*inv);
        ov.z = pack2(o[4]*inv, o[5]*inv);
        ov.w = pack2(o[6]*inv, o[7]*inv);
        *(uint4*)&AO[((size_t)b * NTOK + n) * 64 + 8 * h] = ov;
    }
}

__global__ __launch_bounds__(256) void projcomp_all_kernel(
    const bf16_t* __restrict__ AOr, const bf16_t* __restrict__ AOd,
    const float* __restrict__ w_rp, const float* __restrict__ b_rp,
    const float* __restrict__ w_dp, const float* __restrict__ b_dp,
    const float* __restrict__ w_comp, const float* __restrict__ b_comp,
    float* __restrict__ out)
{
    int tile = blockIdx.x;
    int b    = blockIdx.y;
    __shared__ float A[64][68];
    __shared__ float Bf[64][68];
    __shared__ float Pf[64][68];
    int tid = threadIdx.x;
    int sr = tid >> 4, sc = (tid & 15) * 4;
    int ty = tid >> 4, tx = tid & 15;
    float G[4][4] = {};

    #pragma unroll
    for (int half = 0; half < 2; ++half) {
        const bf16_t* AOx = half ? AOd : AOr;
        const float* Wp   = half ? w_dp : w_rp;
        const float* bp   = half ? b_dp : b_rp;
        #pragma unroll
        for (int rr = 0; rr < 4; ++rr) {
            int r = rr*16 + sr;
            *(float4*)&A[r][sc]  = ld_bf4(&AOx[((size_t)b*NTOK + tile*64 + r)*64 + sc]);
            *(float4*)&Bf[r][sc] = *(const float4*)&Wp[r*64 + sc];
        }
        __syncthreads();
        float acc[4][4] = {};
        #pragma unroll
        for (int k = 0; k < 64; k += 4) {
            float4 xv[4], wv[4];
            #pragma unroll
            for (int i = 0; i < 4; ++i) xv[i] = *(const float4*)&A[4*ty + i][k];
            #pragma unroll
            for (int j = 0; j < 4; ++j) wv[j] = *(const float4*)&Bf[tx + 16*j][k];
            #pragma unroll
            for (int i = 0; i < 4; ++i)
                #pragma unroll
                for (int j = 0; j < 4; ++j)
                    acc[i][j] += xv[i].x*wv[j].x + xv[i].y*wv[j].y + xv[i].z*wv[j].z + xv[i].w*wv[j].w;
        }
        __syncthreads();
        #pragma unroll
        for (int j = 0; j < 4; ++j) {
            float bj = bp[tx + 16*j];
            #pragma unroll
            for (int i = 0; i < 4; ++i)
                Pf[4*ty + i][tx + 16*j] = acc[i][j] + bj;
        }
        #pragma unroll
        for (int rr = 0; rr < 4; ++rr) {
            int r = rr*16 + sr;
            *(float4*)&Bf[r][sc] = *(const float4*)&w_comp[r*128 + half*64 + sc];
        }
        __syncthreads();
        #pragma unroll
        for (int k = 0; k < 64; k += 4) {
            float4 xv[4], wv[4];
            #pragma unroll
            for (int i = 0; i < 4; ++i) xv[i] = *(const float4*)&Pf[4*ty + i][k];
            #pragma unroll
            for (int j = 0; j < 4; ++j) wv[j] = *(const float4*)&Bf[tx + 16*j][k];
            #pragma unroll
            for (int i = 0; i < 4; ++i)
                #pragma unroll
                for (int j = 0; j < 4; ++j)
                    G[i][j] += xv[i].x*wv[j].x + xv[i].y*wv[j].y + xv[i].z*wv[j].z + xv[i].w*wv[j].w;
        }
        __syncthreads();
    }

    #pragma unroll
    for (int j = 0; j < 4; ++j) {
        int o = tx + 16*j;
        float bj = b_comp[o];
        #pragma unroll
        for (int i = 0; i < 4; ++i) {
            int n = tile*64 + 4*ty + i;
            int wi = n / HH, hi = n % HH;
            float x = G[i][j] + bj;
            float g = 0.5f * x * (1.0f + erff(x * 0.70710678118654752f));
            out[((b*C + o)*WW + wi)*HH + hi] = g;
        }
    }
}

// ---------------------------------------------------------------------------
extern "C" void kernel_launch(void* const* d_in, const int* in_sizes, int n_in,
                              void* d_out, int out_size, void* d_ws, size_t ws_size,
                              hipStream_t stream) {
    const float* rgb_fea = (const float*)d_in[0];
    const float* depth   = (const float*)d_in[1];
    const float* w_exp   = (const float*)d_in[2];
    const float* b_exp   = (const float*)d_in[3];
    const float* w_rq    = (const float*)d_in[4];
    const float* w_rk    = (const float*)d_in[5];
    const float* w_rv    = (const float*)d_in[6];
    const float* w_dq    = (const float*)d_in[7];
    const float* w_dk    = (const float*)d_in[8];
    const float* w_dv    = (const float*)d_in[9];
    const float* w_rp    = (const float*)d_in[10];
    const float* b_rp    = (const float*)d_in[11];
    const float* w_dp    = (const float*)d_in[12];
    const float* b_dp    = (const float*)d_in[13];
    const float* w_comp  = (const float*)d_in[14];
    const float* b_comp  = (const float*)d_in[15];
    float* out = (float*)d_out;

    if (ws_size >= 5931264) {
        char* Wb = (char*)d_ws;
        bf16_t* Qb  = (bf16_t*)Wb;                 // [4][8][2304][8] bf16
        bf16_t* Kb  = (bf16_t*)(Wb + 1179648);
        bf16_t* Vb  = (bf16_t*)(Wb + 2359296);
        float* AOr  = (float*)(Wb + 3538944);      // [2][2304][64] fp32
        float* AOd  = (float*)(Wb + 4718592);
        float* W1   = (float*)(Wb + 5898240);
        float* W2   = (float*)(Wb + 5914624);
        float* beff = (float*)(Wb + 5931008);

        wprep_kernel<<<dim3(4, 2), dim3(256), 0, stream>>>(
            w_rp, w_dp, w_comp, b_rp, b_dp, b_comp, W1, W2, beff);
        qkv_kernel<<<dim3(36, 3, 4), dim3(256), 0, stream>>>(
            rgb_fea, depth, w_exp, b_exp,
            w_rq, w_rk, w_rv, w_dq, w_dk, w_dv, Qb, Kb, Vb);
        attn_kernel<<<dim3(9, 8, 4), dim3(256), 0, stream>>>(
            Qb, Kb, Vb, AOr, AOd);
        outcomp_kernel<<<dim3(72, 2), dim3(256), 0, stream>>>(
            AOr, AOd, W1, W2, beff, out);
    } else {
        // R9 big path (proven)
        const size_t BUF = (size_t)BATCH * NTOK * 64;
        bf16_t* Kr  = (bf16_t*)d_ws;
        bf16_t* Vr  = Kr + BUF;
        bf16_t* Kd  = Vr + BUF;
        bf16_t* Vd  = Kd + BUF;
        bf16_t* AOr = Vd + BUF;
        bf16_t* AOd = AOr + BUF;
        kv_all_kernel<<<dim3(36, 2, 4), dim3(256), 0, stream>>>(
            rgb_fea, depth, w_exp, b_exp, w_rk, w_rv, w_dk, w_dv, Kr, Vr, Kd, Vd);
        attn_all_kernel<<<dim3(36, 8, 4), dim3(256), 0, stream>>>(
            rgb_fea, depth, w_exp, b_exp, w_rq, w_dq, Kr, Vr, Kd, Vd, AOr, AOd);
        projcomp_all_kernel<<<dim3(36, 2), dim3(256), 0, stream>>>(
            AOr, AOd, w_rp, b_rp, w_dp, b_dp, w_comp, b_comp, out);
    }
}

// Round 12
// 316.094 us; speedup vs baseline: 1.8296x; 1.0258x over previous
//
#include <hip/hip_runtime.h>
#include <math.h>

// R11: 324us. attn 205us, Occupancy 8%, VALUBusy 48% — 288 blocks x 4 waves
// = 1.1 wave/SIMD; latency-bound (VALU floor ~57us). R12: 8 waves/block,
// in-block 8-way key split + hierarchical LDS merge (same Pm footprint),
// 9 waves/CU. No new ws; qkv/wprep/outcomp unchanged.
#define BATCH 2
#define C 64
#define HH 48
#define WW 48
#define NTOK 2304
#define HEADS 8
#define KVSTRIDE 12

typedef unsigned short bf16_t;
__device__ __forceinline__ bf16_t f2bf(float f) {
    unsigned int u = __float_as_uint(f);
    u = (u + 0x7fffu + ((u >> 16) & 1u)) >> 16;   // RNE
    return (bf16_t)u;
}
__device__ __forceinline__ unsigned pack2(float a, float b) {
    return (unsigned)f2bf(a) | ((unsigned)f2bf(b) << 16);
}
__device__ __forceinline__ float4 ld_bf4(const bf16_t* p) {
    uint2 v = *(const uint2*)p;
    float4 r;
    r.x = __uint_as_float(v.x << 16); r.y = __uint_as_float(v.x & 0xffff0000u);
    r.z = __uint_as_float(v.y << 16); r.w = __uint_as_float(v.y & 0xffff0000u);
    return r;
}
__device__ __forceinline__ void bf8_unpack(uint4 v, float* o) {
    o[0] = __uint_as_float(v.x << 16); o[1] = __uint_as_float(v.x & 0xffff0000u);
    o[2] = __uint_as_float(v.y << 16); o[3] = __uint_as_float(v.y & 0xffff0000u);
    o[4] = __uint_as_float(v.z << 16); o[5] = __uint_as_float(v.z & 0xffff0000u);
    o[6] = __uint_as_float(v.w << 16); o[7] = __uint_as_float(v.w & 0xffff0000u);
}

// Stage one token-row of X. strm 0: rgb transpose gather. strm 1: conv1x1+
// ReLU+bilinear x2 (half-pixel; clamp == jax edge renorm for 24->48).
__device__ __forceinline__ void stage_x_row(
    float* xrow, const float* rgb, const float* dep,
    const float* w_exp, const float* b_exp,
    int b, int n, int strm, int c0, int cstep)
{
    int wi = n / HH, hi = n % HH;
    if (strm == 0) {
        const float* base = rgb + (size_t)b * C * NTOK + (size_t)hi * WW + wi;
        for (int c = c0; c < 64; c += cstep)
            xrow[c] = base[(size_t)c * NTOK];
    } else {
        float cy = 0.5f * hi - 0.25f, cx = 0.5f * wi - 0.25f;
        float fy0 = floorf(cy), fx0 = floorf(cx);
        float fy = cy - fy0, fx = cx - fx0;
        int y0 = max((int)fy0, 0), x0 = max((int)fx0, 0);
        int y1 = min((int)fy0 + 1, 23), x1 = min((int)fx0 + 1, 23);
        const float* dp = dep + b * 576;
        float d00 = dp[y0*24 + x0], d01 = dp[y0*24 + x1];
        float d10 = dp[y1*24 + x0], d11 = dp[y1*24 + x1];
        for (int c = c0; c < 64; c += cstep) {
            float w = w_exp[c], bb = b_exp[c];
            float r00 = fmaxf(w*d00 + bb, 0.f), r01 = fmaxf(w*d01 + bb, 0.f);
            float r10 = fmaxf(w*d10 + bb, 0.f), r11 = fmaxf(w*d11 + bb, 0.f);
            xrow[c] = (1.f-fy)*((1.f-fx)*r00 + fx*r01) + fy*((1.f-fx)*r10 + fx*r11);
        }
    }
}

// ===========================================================================
// MAIN PATH (ws >= 5,931,264 B)
// ===========================================================================

// W1 = Wc[:, :64] @ Wrp ; W2 = Wc[:, 64:] @ Wdp ; beff = Wc@[br;bd] + bc.
__global__ __launch_bounds__(256) void wprep_kernel(
    const float* __restrict__ w_rp, const float* __restrict__ w_dp,
    const float* __restrict__ w_comp,
    const float* __restrict__ b_rp, const float* __restrict__ b_dp,
    const float* __restrict__ b_comp,
    float* __restrict__ W1, float* __restrict__ W2, float* __restrict__ beff)
{
    int bx = blockIdx.x, m = blockIdx.y;
    const float* Wp = m ? w_dp : w_rp;
    float* Wo = m ? W2 : W1;
    __shared__ float Wps[64][68];
    int tid = threadIdx.x;
    int sr = tid >> 4, sc4 = (tid & 15) * 4;
    #pragma unroll
    for (int rr = 0; rr < 4; ++rr) {
        int r = rr*16 + sr;
        *(float4*)&Wps[r][sc4] = *(const float4*)&Wp[r*64 + sc4];
    }
    __syncthreads();
    int r = tid >> 4;
    int o = bx*16 + r;
    int c4 = (tid & 15) * 4;
    float a0 = 0, a1 = 0, a2 = 0, a3 = 0;
    for (int j = 0; j < 64; ++j) {
        float wc = w_comp[o*128 + m*64 + j];
        float4 wp = *(const float4*)&Wps[j][c4];
        a0 += wc*wp.x; a1 += wc*wp.y; a2 += wc*wp.z; a3 += wc*wp.w;
    }
    Wo[o*64 + c4]     = a0;
    Wo[o*64 + c4 + 1] = a1;
    Wo[o*64 + c4 + 2] = a2;
    Wo[o*64 + c4 + 3] = a3;
    if (bx == 0 && m == 0 && tid < 64) {
        float s = b_comp[tid];
        for (int j = 0; j < 64; ++j)
            s += w_comp[tid*128 + j] * b_rp[j] + w_comp[tid*128 + 64 + j] * b_dp[j];
        beff[tid] = s;
    }
}

// prep + one of {Q,K,V} GEMM per (b,strm). grid(36, 3, 4), 256 thr.
// Output [sb=strm*2+b][h][n][8] bf16; Q pre-scaled by 8^-0.5*log2e.
__global__ __launch_bounds__(256) void qkv_kernel(
    const float* __restrict__ rgb, const float* __restrict__ dep,
    const float* __restrict__ w_exp, const float* __restrict__ b_exp,
    const float* __restrict__ w_rq, const float* __restrict__ w_rk, const float* __restrict__ w_rv,
    const float* __restrict__ w_dq, const float* __restrict__ w_dk, const float* __restrict__ w_dv,
    bf16_t* __restrict__ Qb, bf16_t* __restrict__ Kb, bf16_t* __restrict__ Vb)
{
    int tile = blockIdx.x;
    int m    = blockIdx.y;
    int z    = blockIdx.z;
    int b = z >> 1, strm = z & 1;
    const float* W = strm ? (m == 0 ? w_dq : m == 1 ? w_dk : w_dv)
                          : (m == 0 ? w_rq : m == 1 ? w_rk : w_rv);
    bf16_t* O = (m == 0 ? Qb : m == 1 ? Kb : Vb) + (size_t)(strm*2 + b) * NTOK * 64;
    float scale = (m == 0) ? (0.35355339059327373f * 1.4426950408889634f) : 1.0f;

    __shared__ float Xs[64][68];
    __shared__ float Ws[64][68];
    int tid = threadIdx.x;
    {
        int r = tid & 63, c0 = tid >> 6;
        stage_x_row(&Xs[r][0], rgb, dep, w_exp, b_exp, b, tile*64 + r, strm, c0, 4);
    }
    int sr = tid >> 4, sc = (tid & 15) * 4;
    #pragma unroll
    for (int rr = 0; rr < 4; ++rr) {
        int r = rr*16 + sr;
        *(float4*)&Ws[r][sc] = *(const float4*)&W[r*64 + sc];
    }
    __syncthreads();

    int ty = tid >> 4, tx = tid & 15;
    float acc[4][4] = {};
    #pragma unroll
    for (int k = 0; k < 64; k += 4) {
        float4 xv[4], wv4[4];
        #pragma unroll
        for (int i = 0; i < 4; ++i) xv[i] = *(const float4*)&Xs[4*ty + i][k];
        #pragma unroll
        for (int j = 0; j < 4; ++j) wv4[j] = *(const float4*)&Ws[tx + 16*j][k];
        #pragma unroll
        for (int i = 0; i < 4; ++i)
            #pragma unroll
            for (int j = 0; j < 4; ++j)
                acc[i][j] += xv[i].x*wv4[j].x + xv[i].y*wv4[j].y + xv[i].z*wv4[j].z + xv[i].w*wv4[j].w;
    }
    #pragma unroll
    for (int j = 0; j < 4; ++j) {
        int o = tx + 16*j;
        int h = o >> 3, d = o & 7;
        #pragma unroll
        for (int i = 0; i < 4; ++i) {
            int n = tile*64 + 4*ty + i;
            O[((size_t)h * NTOK + n) * 8 + d] = f2bf(acc[i][j] * scale);
        }
    }
}

// Flash attention: no-max softmax, R=4 queries/lane, 8-way in-block key split.
// grid(9, 8, 4): qt(256 q) x head x (b*2+which). 512 thr = 8 waves.
// Wave w owns keys [288w, 288w+288) in 9 x 32-key tiles staged (lanes t<32)
// to its PRIVATE LDS quadrant — no barriers in the loop. Hierarchical merge:
// waves 4-7 dump Pm, waves 0-3 add in place, 256 threads finalize (exact for
// no-max softmax). AO stored normalized fp32 [b][n][64].
__global__ __launch_bounds__(512) void attn_kernel(
    const bf16_t* __restrict__ Qb, const bf16_t* __restrict__ Kb,
    const bf16_t* __restrict__ Vb,
    float* __restrict__ AOr, float* __restrict__ AOd)
{
    int qt = blockIdx.x;          // 0..8
    int h  = blockIdx.y;          // 0..7
    int z  = blockIdx.z;          // b*2 + which
    int b = z >> 1, which = z & 1;
    int qsb = which * 2 + b;
    int ksb = (1 - which) * 2 + b;
    const bf16_t* Q = Qb + ((size_t)qsb * 8 + h) * NTOK * 8;
    const bf16_t* K = Kb + ((size_t)ksb * 8 + h) * NTOK * 8;
    const bf16_t* V = Vb + ((size_t)ksb * 8 + h) * NTOK * 8;
    float* AO = which ? AOd : AOr;

    __shared__ uint4 KsB[8][32];      // [wave][key] 8 x bf16 K (4 KB)
    __shared__ uint4 VsB[8][32];      //                     V (4 KB)
    __shared__ float Pm[4][256][9];   // merge partials (36 KB)

    int tid = threadIdx.x;
    int t = tid & 63, w = tid >> 6;   // 8 waves
    int n0 = qt * 256;

    float q[4][8];
    #pragma unroll
    for (int j = 0; j < 4; ++j)
        bf8_unpack(*(const uint4*)&Q[(size_t)(n0 + 64*j + t) * 8], q[j]);

    float l[4] = {0.f, 0.f, 0.f, 0.f};
    float acc[4][8] = {};

    #pragma unroll 1
    for (int kt = 0; kt < 9; ++kt) {
        if (t < 32) {
            int key = w*288 + kt*32 + t;
            KsB[w][t] = *(const uint4*)&K[(size_t)key * 8];
            VsB[w][t] = *(const uint4*)&V[(size_t)key * 8];
        }
        // wave-synchronous: same-wave LDS RAW ordered by lgkmcnt; no barrier.
        #pragma unroll 2
        for (int u = 0; u < 32; ++u) {
            float kf[8], vf[8];
            bf8_unpack(KsB[w][u], kf);
            bf8_unpack(VsB[w][u], vf);
            #pragma unroll
            for (int j = 0; j < 4; ++j) {
                float s = q[j][0]*kf[0] + q[j][1]*kf[1] + q[j][2]*kf[2] + q[j][3]*kf[3]
                        + q[j][4]*kf[4] + q[j][5]*kf[5] + q[j][6]*kf[6] + q[j][7]*kf[7];
                float p = __builtin_amdgcn_exp2f(s);
                l[j] += p;
                #pragma unroll
                for (int d = 0; d < 8; ++d) acc[j][d] += p * vf[d];
            }
        }
    }

    // hierarchical in-block merge (plain sums — exact for no-max partials)
    __syncthreads();
    if (w >= 4) {
        #pragma unroll
        for (int j = 0; j < 4; ++j) {
            float* p = &Pm[w - 4][j*64 + t][0];
            #pragma unroll
            for (int d = 0; d < 8; ++d) p[d] = acc[j][d];
            p[8] = l[j];
        }
    }
    __syncthreads();
    if (w < 4) {
        #pragma unroll
        for (int j = 0; j < 4; ++j) {
            float* p = &Pm[w][j*64 + t][0];
            #pragma unroll
            for (int d = 0; d < 8; ++d) p[d] += acc[j][d];
            p[8] += l[j];
        }
    }
    __syncthreads();
    if (tid < 256) {
        int i = tid;
        float L = 0.f, o[8] = {};
        #pragma unroll
        for (int v = 0; v < 4; ++v) {
            const float* p = &Pm[v][i][0];
            #pragma unroll
            for (int d = 0; d < 8; ++d) o[d] += p[d];
            L += p[8];
        }
        float inv = 1.0f / L;
        float* dst = &AO[((size_t)b * NTOK + n0 + i) * 64 + 8 * h];
        *(float4*)&dst[0] = make_float4(o[0]*inv, o[1]*inv, o[2]*inv, o[3]*inv);
        *(float4*)&dst[4] = make_float4(o[4]*inv, o[5]*inv, o[6]*inv, o[7]*inv);
    }
}

// Fused 2x K=64 GEMM (W1,W2) + beff + GELU + transposed store.
// grid(72, 2): 32-token tiles x batch. AO rows already normalized fp32.
__global__ __launch_bounds__(256) void outcomp_kernel(
    const float* __restrict__ AOr, const float* __restrict__ AOd,
    const float* __restrict__ W1, const float* __restrict__ W2,
    const float* __restrict__ beff, float* __restrict__ out)
{
    int tile = blockIdx.x;       // 0..71
    int b    = blockIdx.y;
    int n0 = tile * 32;
    __shared__ float Ar[32][68];
    __shared__ float Ad[32][68];
    __shared__ float W1s[64][68];
    __shared__ float W2s[64][68];
    int tid = threadIdx.x;
    #pragma unroll
    for (int pass = 0; pass < 2; ++pass) {
        int idx = tid + pass*256;
        int row = idx >> 4, c4 = (idx & 15) * 4;
        *(float4*)&Ar[row][c4] = *(const float4*)&AOr[((size_t)b*NTOK + n0 + row)*64 + c4];
        *(float4*)&Ad[row][c4] = *(const float4*)&AOd[((size_t)b*NTOK + n0 + row)*64 + c4];
    }
    {
        int sr = tid >> 4, sc4 = (tid & 15) * 4;
        #pragma unroll
        for (int rr = 0; rr < 4; ++rr) {
            int r = rr*16 + sr;
            *(float4*)&W1s[r][sc4] = *(const float4*)&W1[r*64 + sc4];
            *(float4*)&W2s[r][sc4] = *(const float4*)&W2[r*64 + sc4];
        }
    }
    __syncthreads();

    int tx = tid & 15, ty = tid >> 4;
    float g[2][4] = {};
    #pragma unroll
    for (int k = 0; k < 64; k += 4) {
        float4 xr0 = *(const float4*)&Ar[2*ty][k];
        float4 xr1 = *(const float4*)&Ar[2*ty + 1][k];
        float4 xd0 = *(const float4*)&Ad[2*ty][k];
        float4 xd1 = *(const float4*)&Ad[2*ty + 1][k];
        #pragma unroll
        for (int jj = 0; jj < 4; ++jj) {
            float4 w1 = *(const float4*)&W1s[tx + 16*jj][k];
            float4 w2 = *(const float4*)&W2s[tx + 16*jj][k];
            g[0][jj] += xr0.x*w1.x + xr0.y*w1.y + xr0.z*w1.z + xr0.w*w1.w
                      + xd0.x*w2.x + xd0.y*w2.y + xd0.z*w2.z + xd0.w*w2.w;
            g[1][jj] += xr1.x*w1.x + xr1.y*w1.y + xr1.z*w1.z + xr1.w*w1.w
                      + xd1.x*w2.x + xd1.y*w2.y + xd1.z*w2.z + xd1.w*w2.w;
        }
    }
    #pragma unroll
    for (int jj = 0; jj < 4; ++jj) {
        int o = tx + 16*jj;
        float be = beff[o];
        #pragma unroll
        for (int i = 0; i < 2; ++i) {
            int n = n0 + 2*ty + i;
            int wi = n / HH, hi = n % HH;
            float x = g[i][jj] + be;
            float gl = 0.5f * x * (1.0f + erff(x * 0.70710678118654752f));
            out[((b*C + o)*WW + wi)*HH + hi] = gl;
        }
    }
}

// ===========================================================================
// FALLBACK (R9 big path, proven): ws >= 3,538,944 B.
// ===========================================================================
__global__ __launch_bounds__(256) void kv_all_kernel(
    const float* __restrict__ rgb, const float* __restrict__ dep,
    const float* __restrict__ w_exp, const float* __restrict__ b_exp,
    const float* __restrict__ w_rk, const float* __restrict__ w_rv,
    const float* __restrict__ w_dk, const float* __restrict__ w_dv,
    bf16_t* __restrict__ Kr, bf16_t* __restrict__ Vr,
    bf16_t* __restrict__ Kd, bf16_t* __restrict__ Vd)
{
    int tile = blockIdx.x;
    int m    = blockIdx.y;
    int z    = blockIdx.z;
    int b = z >> 1, strm = z & 1;
    const float* W = strm ? (m ? w_dv : w_dk) : (m ? w_rv : w_rk);
    bf16_t* O = (strm ? (m ? Vd : Kd) : (m ? Vr : Kr))
              + ((size_t)b * NTOK + tile * 64) * 64;

    __shared__ float Xs[64][68];
    __shared__ float Ws[64][68];
    int tid = threadIdx.x;
    {
        int r = tid & 63, c0 = tid >> 6;
        stage_x_row(&Xs[r][0], rgb, dep, w_exp, b_exp, b, tile*64 + r, strm, c0, 4);
    }
    int sr = tid >> 4, sc = (tid & 15) * 4;
    #pragma unroll
    for (int rr = 0; rr < 4; ++rr) {
        int r = rr*16 + sr;
        *(float4*)&Ws[r][sc] = *(const float4*)&W[r*64 + sc];
    }
    __syncthreads();

    int ty = tid >> 4, tx = tid & 15;
    float acc[4][4] = {};
    #pragma unroll
    for (int k = 0; k < 64; k += 4) {
        float4 xv[4], wv4[4];
        #pragma unroll
        for (int i = 0; i < 4; ++i) xv[i] = *(const float4*)&Xs[4*ty + i][k];
        #pragma unroll
        for (int j = 0; j < 4; ++j) wv4[j] = *(const float4*)&Ws[tx + 16*j][k];
        #pragma unroll
        for (int i = 0; i < 4; ++i)
            #pragma unroll
            for (int j = 0; j < 4; ++j)
                acc[i][j] += xv[i].x*wv4[j].x + xv[i].y*wv4[j].y + xv[i].z*wv4[j].z + xv[i].w*wv4[j].w;
    }
    #pragma unroll
    for (int i = 0; i < 4; ++i)
        #pragma unroll
        for (int j = 0; j < 4; ++j)
            O[(4*ty + i)*64 + tx + 16*j] = f2bf(acc[i][j]);
}

__global__ __launch_bounds__(256) void attn_all_kernel(
    const float* __restrict__ rgb, const float* __restrict__ dep,
    const float* __restrict__ w_exp, const float* __restrict__ b_exp,
    const float* __restrict__ w_rq, const float* __restrict__ w_dq,
    const bf16_t* __restrict__ Kr, const bf16_t* __restrict__ Vr,
    const bf16_t* __restrict__ Kd, const bf16_t* __restrict__ Vd,
    bf16_t* __restrict__ AOr, bf16_t* __restrict__ AOd)
{
    int qt = blockIdx.x;
    int h  = blockIdx.y;
    int z  = blockIdx.z;
    int b = z >> 1, which = z & 1;
    const float* wq = which ? w_dq : w_rq;
    const bf16_t* K = which ? Kr : Kd;
    const bf16_t* V = which ? Vr : Vd;
    bf16_t* AO      = which ? AOd : AOr;

    __shared__ float Xs[64][68];
    __shared__ float Wqs[8][64];
    __shared__ __align__(16) float Ks[4][64][KVSTRIDE];
    __shared__ __align__(16) float Vs[4][64][KVSTRIDE];

    int tid = threadIdx.x;
    int t = tid & 63;
    int w = tid >> 6;
    int n = qt * 64 + t;

    stage_x_row(&Xs[t][0], rgb, dep, w_exp, b_exp, b, n, which == 0 ? 0 : 1, w, 4);
    if (w == 0) {
        #pragma unroll
        for (int d = 0; d < 8; ++d) Wqs[d][t] = wq[(8*h + d)*64 + t];
    }
    __syncthreads();

    const float sc = 0.35355339059327373f * 1.4426950408889634f;
    float q[8];
    #pragma unroll
    for (int d = 0; d < 8; ++d) {
        float s = 0.f;
        #pragma unroll 8
        for (int c = 0; c < 64; ++c) s += Xs[t][c] * Wqs[d][c];
        q[d] = s * sc;
    }

    float mrun = -INFINITY, l = 0.f;
    float acc[8] = {};

    #pragma unroll 1
    for (int st = 0; st < 9; ++st) {
        __syncthreads();
        {
            size_t g = ((size_t)b * NTOK + (w*576 + st*64 + t)) * 64 + 8 * h;
            *(float4*)&Ks[w][t][0] = ld_bf4(&K[g]);
            *(float4*)&Ks[w][t][4] = ld_bf4(&K[g + 4]);
            *(float4*)&Vs[w][t][0] = ld_bf4(&V[g]);
            *(float4*)&Vs[w][t][4] = ld_bf4(&V[g + 4]);
        }
        __syncthreads();

        for (int g8 = 0; g8 < 8; ++g8) {
            float s[8];
            #pragma unroll
            for (int u = 0; u < 8; ++u) {
                const float4 ka = *(const float4*)&Ks[w][g8*8 + u][0];
                const float4 kb = *(const float4*)&Ks[w][g8*8 + u][4];
                s[u] = q[0]*ka.x + q[1]*ka.y + q[2]*ka.z + q[3]*ka.w
                     + q[4]*kb.x + q[5]*kb.y + q[6]*kb.z + q[7]*kb.w;
            }
            float tm = fmaxf(fmaxf(fmaxf(s[0],s[1]), fmaxf(s[2],s[3])),
                             fmaxf(fmaxf(s[4],s[5]), fmaxf(s[6],s[7])));
            float mn = fmaxf(mrun, tm);
            float alpha = __builtin_amdgcn_exp2f(mrun - mn);
            float ps = 0.f;
            #pragma unroll
            for (int u = 0; u < 8; ++u) { s[u] = __builtin_amdgcn_exp2f(s[u] - mn); ps += s[u]; }
            l = l * alpha + ps;
            #pragma unroll
            for (int d = 0; d < 8; ++d) acc[d] *= alpha;
            #pragma unroll
            for (int u = 0; u < 8; ++u) {
                const float4 va = *(const float4*)&Vs[w][g8*8 + u][0];
                const float4 vb = *(const float4*)&Vs[w][g8*8 + u][4];
                acc[0] += s[u]*va.x; acc[1] += s[u]*va.y; acc[2] += s[u]*va.z; acc[3] += s[u]*va.w;
                acc[4] += s[u]*vb.x; acc[5] += s[u]*vb.y; acc[6] += s[u]*vb.z; acc[7] += s[u]*vb.w;
            }
            mrun = mn;
        }
    }

    float* part = &Xs[0][0];
    __syncthreads();
    {
        float* p = &part[(w*64 + t) * 10];
        p[0] = mrun; p[1] = l;
        #pragma unroll
        for (int d = 0; d < 8; ++d) p[2 + d] = acc[d];
    }
    __syncthreads();
    if (tid < 64) {
        float M = -INFINITY;
        #pragma unroll
        for (int v = 0; v < 4; ++v) M = fmaxf(M, part[(v*64 + t)*10]);
        float L = 0.f, o[8] = {};
        #pragma unroll
        for (int v = 0; v < 4; ++v) {
            const float* p = &part[(v*64 + t)*10];
            float al = __builtin_amdgcn_exp2f(p[0] - M);
            L += p[1] * al;
            #pragma unroll
            for (int d = 0; d < 8; ++d) o[d] += p[2 + d] * al;
        }
        float inv = 1.0f / L;
        uint4 ov;
        ov.x = pack2(o[0]*inv, o[1]*inv);
        ov.y = pack2(o[2]*inv, o[3]*inv);
        ov.z = pack2(o[4]*inv, o[5]*inv);
        ov.w = pack2(o[6]*inv, o[7]*inv);
        *(uint4*)&AO[((size_t)b * NTOK + n) * 64 + 8 * h] = ov;
    }
}

__global__ __launch_bounds__(256) void projcomp_all_kernel(
    const bf16_t* __restrict__ AOr, const bf16_t* __restrict__ AOd,
    const float* __restrict__ w_rp, const float* __restrict__ b_rp,
    const float* __restrict__ w_dp, const float* __restrict__ b_dp,
    const float* __restrict__ w_comp, const float* __restrict__ b_comp,
    float* __restrict__ out)
{
    int tile = blockIdx.x;
    int b    = blockIdx.y;
    __shared__ float A[64][68];
    __shared__ float Bf[64][68];
    __shared__ float Pf[64][68];
    int tid = threadIdx.x;
    int sr = tid >> 4, sc = (tid & 15) * 4;
    int ty = tid >> 4, tx = tid & 15;
    float G[4][4] = {};

    #pragma unroll
    for (int half = 0; half < 2; ++half) {
        const bf16_t* AOx = half ? AOd : AOr;
        const float* Wp   = half ? w_dp : w_rp;
        const float* bp   = half ? b_dp : b_rp;
        #pragma unroll
        for (int rr = 0; rr < 4; ++rr) {
            int r = rr*16 + sr;
            *(float4*)&A[r][sc]  = ld_bf4(&AOx[((size_t)b*NTOK + tile*64 + r)*64 + sc]);
            *(float4*)&Bf[r][sc] = *(const float4*)&Wp[r*64 + sc];
        }
        __syncthreads();
        float acc[4][4] = {};
        #pragma unroll
        for (int k = 0; k < 64; k += 4) {
            float4 xv[4], wv[4];
            #pragma unroll
            for (int i = 0; i < 4; ++i) xv[i] = *(const float4*)&A[4*ty + i][k];
            #pragma unroll
            for (int j = 0; j < 4; ++j) wv[j] = *(const float4*)&Bf[tx + 16*j][k];
            #pragma unroll
            for (int i = 0; i < 4; ++i)
                #pragma unroll
                for (int j = 0; j < 4; ++j)
                    acc[i][j] += xv[i].x*wv[j].x + xv[i].y*wv[j].y + xv[i].z*wv[j].z + xv[i].w*wv[j].w;
        }
        __syncthreads();
        #pragma unroll
        for (int j = 0; j < 4; ++j) {
            float bj = bp[tx + 16*j];
            #pragma unroll
            for (int i = 0; i < 4; ++i)
                Pf[4*ty + i][tx + 16*j] = acc[i][j] + bj;
        }
        #pragma unroll
        for (int rr = 0; rr < 4; ++rr) {
            int r = rr*16 + sr;
            *(float4*)&Bf[r][sc] = *(const float4*)&w_comp[r*128 + half*64 + sc];
        }
        __syncthreads();
        #pragma unroll
        for (int k = 0; k < 64; k += 4) {
            float4 xv[4], wv[4];
            #pragma unroll
            for (int i = 0; i < 4; ++i) xv[i] = *(const float4*)&Pf[4*ty + i][k];
            #pragma unroll
            for (int j = 0; j < 4; ++j) wv[j] = *(const float4*)&Bf[tx + 16*j][k];
            #pragma unroll
            for (int i = 0; i < 4; ++i)
                #pragma unroll
                for (int j = 0; j < 4; ++j)
                    G[i][j] += xv[i].x*wv[j].x + xv[i].y*wv[j].y + xv[i].z*wv[j].z + xv[i].w*wv[j].w;
        }
        __syncthreads();
    }

    #pragma unroll
    for (int j = 0; j < 4; ++j) {
        int o = tx + 16*j;
        float bj = b_comp[o];
        #pragma unroll
        for (int i = 0; i < 4; ++i) {
            int n = tile*64 + 4*ty + i;
            int wi = n / HH, hi = n % HH;
            float x = G[i][j] + bj;
            float g = 0.5f * x * (1.0f + erff(x * 0.70710678118654752f));
            out[((b*C + o)*WW + wi)*HH + hi] = g;
        }
    }
}

// ---------------------------------------------------------------------------
extern "C" void kernel_launch(void* const* d_in, const int* in_sizes, int n_in,
                              void* d_out, int out_size, void* d_ws, size_t ws_size,
                              hipStream_t stream) {
    const float* rgb_fea = (const float*)d_in[0];
    const float* depth   = (const float*)d_in[1];
    const float* w_exp   = (const float*)d_in[2];
    const float* b_exp   = (const float*)d_in[3];
    const float* w_rq    = (const float*)d_in[4];
    const float* w_rk    = (const float*)d_in[5];
    const float* w_rv    = (const float*)d_in[6];
    const float* w_dq    = (const float*)d_in[7];
    const float* w_dk    = (const float*)d_in[8];
    const float* w_dv    = (const float*)d_in[9];
    const float* w_rp    = (const float*)d_in[10];
    const float* b_rp    = (const float*)d_in[11];
    const float* w_dp    = (const float*)d_in[12];
    const float* b_dp    = (const float*)d_in[13];
    const float* w_comp  = (const float*)d_in[14];
    const float* b_comp  = (const float*)d_in[15];
    float* out = (float*)d_out;

    if (ws_size >= 5931264) {
        char* Wb = (char*)d_ws;
        bf16_t* Qb  = (bf16_t*)Wb;                 // [4][8][2304][8] bf16
        bf16_t* Kb  = (bf16_t*)(Wb + 1179648);
        bf16_t* Vb  = (bf16_t*)(Wb + 2359296);
        float* AOr  = (float*)(Wb + 3538944);      // [2][2304][64] fp32
        float* AOd  = (float*)(Wb + 4718592);
        float* W1   = (float*)(Wb + 5898240);
        float* W2   = (float*)(Wb + 5914624);
        float* beff = (float*)(Wb + 5931008);

        wprep_kernel<<<dim3(4, 2), dim3(256), 0, stream>>>(
            w_rp, w_dp, w_comp, b_rp, b_dp, b_comp, W1, W2, beff);
        qkv_kernel<<<dim3(36, 3, 4), dim3(256), 0, stream>>>(
            rgb_fea, depth, w_exp, b_exp,
            w_rq, w_rk, w_rv, w_dq, w_dk, w_dv, Qb, Kb, Vb);
        attn_kernel<<<dim3(9, 8, 4), dim3(512), 0, stream>>>(
            Qb, Kb, Vb, AOr, AOd);
        outcomp_kernel<<<dim3(72, 2), dim3(256), 0, stream>>>(
            AOr, AOd, W1, W2, beff, out);
    } else {
        // R9 big path (proven)
        const size_t BUF = (size_t)BATCH * NTOK * 64;
        bf16_t* Kr  = (bf16_t*)d_ws;
        bf16_t* Vr  = Kr + BUF;
        bf16_t* Kd  = Vr + BUF;
        bf16_t* Vd  = Kd + BUF;
        bf16_t* AOr = Vd + BUF;
        bf16_t* AOd = AOr + BUF;
        kv_all_kernel<<<dim3(36, 2, 4), dim3(256), 0, stream>>>(
            rgb_fea, depth, w_exp, b_exp, w_rk, w_rv, w_dk, w_dv, Kr, Vr, Kd, Vd);
        attn_all_kernel<<<dim3(36, 8, 4), dim3(256), 0, stream>>>(
            rgb_fea, depth, w_exp, b_exp, w_rq, w_dq, Kr, Vr, Kd, Vd, AOr, AOd);
        projcomp_all_kernel<<<dim3(36, 2), dim3(256), 0, stream>>>(
            AOr, AOd, w_rp, b_rp, w_dp, b_dp, w_comp, b_comp, out);
    }
}

// Round 13
// 290.697 us; speedup vs baseline: 1.9895x; 1.0874x over previous
//
#include <hip/hip_runtime.h>
#include <math.h>

// R12: 316us; attn 199us, VALUBusy 49%, VGPR 60 (< 64 live state -> scratch
// spill ate the 8-wave gain). R13: R=2 queries/lane (32-reg state, no spill),
// 128-query blocks -> grid(18,8,4)=576 blocks x 8 waves = 18 waves/CU;
// staging uses all 64 lanes; __launch_bounds__(512,1). Rest unchanged.
#define BATCH 2
#define C 64
#define HH 48
#define WW 48
#define NTOK 2304
#define HEADS 8
#define KVSTRIDE 12

typedef unsigned short bf16_t;
__device__ __forceinline__ bf16_t f2bf(float f) {
    unsigned int u = __float_as_uint(f);
    u = (u + 0x7fffu + ((u >> 16) & 1u)) >> 16;   // RNE
    return (bf16_t)u;
}
__device__ __forceinline__ unsigned pack2(float a, float b) {
    return (unsigned)f2bf(a) | ((unsigned)f2bf(b) << 16);
}
__device__ __forceinline__ float4 ld_bf4(const bf16_t* p) {
    uint2 v = *(const uint2*)p;
    float4 r;
    r.x = __uint_as_float(v.x << 16); r.y = __uint_as_float(v.x & 0xffff0000u);
    r.z = __uint_as_float(v.y << 16); r.w = __uint_as_float(v.y & 0xffff0000u);
    return r;
}
__device__ __forceinline__ void bf8_unpack(uint4 v, float* o) {
    o[0] = __uint_as_float(v.x << 16); o[1] = __uint_as_float(v.x & 0xffff0000u);
    o[2] = __uint_as_float(v.y << 16); o[3] = __uint_as_float(v.y & 0xffff0000u);
    o[4] = __uint_as_float(v.z << 16); o[5] = __uint_as_float(v.z & 0xffff0000u);
    o[6] = __uint_as_float(v.w << 16); o[7] = __uint_as_float(v.w & 0xffff0000u);
}

// Stage one token-row of X. strm 0: rgb transpose gather. strm 1: conv1x1+
// ReLU+bilinear x2 (half-pixel; clamp == jax edge renorm for 24->48).
__device__ __forceinline__ void stage_x_row(
    float* xrow, const float* rgb, const float* dep,
    const float* w_exp, const float* b_exp,
    int b, int n, int strm, int c0, int cstep)
{
    int wi = n / HH, hi = n % HH;
    if (strm == 0) {
        const float* base = rgb + (size_t)b * C * NTOK + (size_t)hi * WW + wi;
        for (int c = c0; c < 64; c += cstep)
            xrow[c] = base[(size_t)c * NTOK];
    } else {
        float cy = 0.5f * hi - 0.25f, cx = 0.5f * wi - 0.25f;
        float fy0 = floorf(cy), fx0 = floorf(cx);
        float fy = cy - fy0, fx = cx - fx0;
        int y0 = max((int)fy0, 0), x0 = max((int)fx0, 0);
        int y1 = min((int)fy0 + 1, 23), x1 = min((int)fx0 + 1, 23);
        const float* dp = dep + b * 576;
        float d00 = dp[y0*24 + x0], d01 = dp[y0*24 + x1];
        float d10 = dp[y1*24 + x0], d11 = dp[y1*24 + x1];
        for (int c = c0; c < 64; c += cstep) {
            float w = w_exp[c], bb = b_exp[c];
            float r00 = fmaxf(w*d00 + bb, 0.f), r01 = fmaxf(w*d01 + bb, 0.f);
            float r10 = fmaxf(w*d10 + bb, 0.f), r11 = fmaxf(w*d11 + bb, 0.f);
            xrow[c] = (1.f-fy)*((1.f-fx)*r00 + fx*r01) + fy*((1.f-fx)*r10 + fx*r11);
        }
    }
}

// ===========================================================================
// MAIN PATH (ws >= 5,931,264 B)
// ===========================================================================

// W1 = Wc[:, :64] @ Wrp ; W2 = Wc[:, 64:] @ Wdp ; beff = Wc@[br;bd] + bc.
__global__ __launch_bounds__(256) void wprep_kernel(
    const float* __restrict__ w_rp, const float* __restrict__ w_dp,
    const float* __restrict__ w_comp,
    const float* __restrict__ b_rp, const float* __restrict__ b_dp,
    const float* __restrict__ b_comp,
    float* __restrict__ W1, float* __restrict__ W2, float* __restrict__ beff)
{
    int bx = blockIdx.x, m = blockIdx.y;
    const float* Wp = m ? w_dp : w_rp;
    float* Wo = m ? W2 : W1;
    __shared__ float Wps[64][68];
    int tid = threadIdx.x;
    int sr = tid >> 4, sc4 = (tid & 15) * 4;
    #pragma unroll
    for (int rr = 0; rr < 4; ++rr) {
        int r = rr*16 + sr;
        *(float4*)&Wps[r][sc4] = *(const float4*)&Wp[r*64 + sc4];
    }
    __syncthreads();
    int r = tid >> 4;
    int o = bx*16 + r;
    int c4 = (tid & 15) * 4;
    float a0 = 0, a1 = 0, a2 = 0, a3 = 0;
    for (int j = 0; j < 64; ++j) {
        float wc = w_comp[o*128 + m*64 + j];
        float4 wp = *(const float4*)&Wps[j][c4];
        a0 += wc*wp.x; a1 += wc*wp.y; a2 += wc*wp.z; a3 += wc*wp.w;
    }
    Wo[o*64 + c4]     = a0;
    Wo[o*64 + c4 + 1] = a1;
    Wo[o*64 + c4 + 2] = a2;
    Wo[o*64 + c4 + 3] = a3;
    if (bx == 0 && m == 0 && tid < 64) {
        float s = b_comp[tid];
        for (int j = 0; j < 64; ++j)
            s += w_comp[tid*128 + j] * b_rp[j] + w_comp[tid*128 + 64 + j] * b_dp[j];
        beff[tid] = s;
    }
}

// prep + one of {Q,K,V} GEMM per (b,strm). grid(36, 3, 4), 256 thr.
// Output [sb=strm*2+b][h][n][8] bf16; Q pre-scaled by 8^-0.5*log2e.
__global__ __launch_bounds__(256) void qkv_kernel(
    const float* __restrict__ rgb, const float* __restrict__ dep,
    const float* __restrict__ w_exp, const float* __restrict__ b_exp,
    const float* __restrict__ w_rq, const float* __restrict__ w_rk, const float* __restrict__ w_rv,
    const float* __restrict__ w_dq, const float* __restrict__ w_dk, const float* __restrict__ w_dv,
    bf16_t* __restrict__ Qb, bf16_t* __restrict__ Kb, bf16_t* __restrict__ Vb)
{
    int tile = blockIdx.x;
    int m    = blockIdx.y;
    int z    = blockIdx.z;
    int b = z >> 1, strm = z & 1;
    const float* W = strm ? (m == 0 ? w_dq : m == 1 ? w_dk : w_dv)
                          : (m == 0 ? w_rq : m == 1 ? w_rk : w_rv);
    bf16_t* O = (m == 0 ? Qb : m == 1 ? Kb : Vb) + (size_t)(strm*2 + b) * NTOK * 64;
    float scale = (m == 0) ? (0.35355339059327373f * 1.4426950408889634f) : 1.0f;

    __shared__ float Xs[64][68];
    __shared__ float Ws[64][68];
    int tid = threadIdx.x;
    {
        int r = tid & 63, c0 = tid >> 6;
        stage_x_row(&Xs[r][0], rgb, dep, w_exp, b_exp, b, tile*64 + r, strm, c0, 4);
    }
    int sr = tid >> 4, sc = (tid & 15) * 4;
    #pragma unroll
    for (int rr = 0; rr < 4; ++rr) {
        int r = rr*16 + sr;
        *(float4*)&Ws[r][sc] = *(const float4*)&W[r*64 + sc];
    }
    __syncthreads();

    int ty = tid >> 4, tx = tid & 15;
    float acc[4][4] = {};
    #pragma unroll
    for (int k = 0; k < 64; k += 4) {
        float4 xv[4], wv4[4];
        #pragma unroll
        for (int i = 0; i < 4; ++i) xv[i] = *(const float4*)&Xs[4*ty + i][k];
        #pragma unroll
        for (int j = 0; j < 4; ++j) wv4[j] = *(const float4*)&Ws[tx + 16*j][k];
        #pragma unroll
        for (int i = 0; i < 4; ++i)
            #pragma unroll
            for (int j = 0; j < 4; ++j)
                acc[i][j] += xv[i].x*wv4[j].x + xv[i].y*wv4[j].y + xv[i].z*wv4[j].z + xv[i].w*wv4[j].w;
    }
    #pragma unroll
    for (int j = 0; j < 4; ++j) {
        int o = tx + 16*j;
        int h = o >> 3, d = o & 7;
        #pragma unroll
        for (int i = 0; i < 4; ++i) {
            int n = tile*64 + 4*ty + i;
            O[((size_t)h * NTOK + n) * 8 + d] = f2bf(acc[i][j] * scale);
        }
    }
}

// Flash attention: no-max softmax, R=2 queries/lane, 8-way in-block key split.
// grid(18, 8, 4): qt(128 q) x head x (b*2+which). 512 thr = 8 waves.
// Wave w owns keys [288w, 288w+288) in 9 x 32-key tiles; lanes t<32 stage K,
// t>=32 stage V into the wave's PRIVATE LDS quadrant — no barriers in loop.
// Hierarchical merge (plain sums, exact for no-max): waves 4-7 dump, 0-3 add,
// 128 threads finalize. AO stored normalized fp32 [b][n][64].
__global__ __launch_bounds__(512, 1) void attn_kernel(
    const bf16_t* __restrict__ Qb, const bf16_t* __restrict__ Kb,
    const bf16_t* __restrict__ Vb,
    float* __restrict__ AOr, float* __restrict__ AOd)
{
    int qt = blockIdx.x;          // 0..17
    int h  = blockIdx.y;          // 0..7
    int z  = blockIdx.z;          // b*2 + which
    int b = z >> 1, which = z & 1;
    int qsb = which * 2 + b;
    int ksb = (1 - which) * 2 + b;
    const bf16_t* Q = Qb + ((size_t)qsb * 8 + h) * NTOK * 8;
    const bf16_t* K = Kb + ((size_t)ksb * 8 + h) * NTOK * 8;
    const bf16_t* V = Vb + ((size_t)ksb * 8 + h) * NTOK * 8;
    float* AO = which ? AOd : AOr;

    __shared__ uint4 KsB[8][32];      // [wave][key] 8 x bf16 K (4 KB)
    __shared__ uint4 VsB[8][32];      //                     V (4 KB)
    __shared__ float Pm[4][128][9];   // merge partials (18.4 KB)

    int tid = threadIdx.x;
    int t = tid & 63, w = tid >> 6;   // 8 waves
    int n0 = qt * 128;

    float q[2][8];
    #pragma unroll
    for (int j = 0; j < 2; ++j)
        bf8_unpack(*(const uint4*)&Q[(size_t)(n0 + 64*j + t) * 8], q[j]);

    float l[2] = {0.f, 0.f};
    float acc[2][8] = {};

    #pragma unroll 1
    for (int kt = 0; kt < 9; ++kt) {
        {
            int key = w*288 + kt*32 + (t & 31);
            if (t < 32) KsB[w][t]      = *(const uint4*)&K[(size_t)key * 8];
            else        VsB[w][t - 32] = *(const uint4*)&V[(size_t)key * 8];
        }
        // wave-synchronous: same-wave LDS RAW ordered by lgkmcnt; no barrier.
        #pragma unroll 2
        for (int u = 0; u < 32; ++u) {
            float kf[8], vf[8];
            bf8_unpack(KsB[w][u], kf);
            bf8_unpack(VsB[w][u], vf);
            #pragma unroll
            for (int j = 0; j < 2; ++j) {
                float s = q[j][0]*kf[0] + q[j][1]*kf[1] + q[j][2]*kf[2] + q[j][3]*kf[3]
                        + q[j][4]*kf[4] + q[j][5]*kf[5] + q[j][6]*kf[6] + q[j][7]*kf[7];
                float p = __builtin_amdgcn_exp2f(s);
                l[j] += p;
                #pragma unroll
                for (int d = 0; d < 8; ++d) acc[j][d] += p * vf[d];
            }
        }
    }

    // hierarchical in-block merge (plain sums — exact for no-max partials)
    __syncthreads();
    if (w >= 4) {
        #pragma unroll
        for (int j = 0; j < 2; ++j) {
            float* p = &Pm[w - 4][j*64 + t][0];
            #pragma unroll
            for (int d = 0; d < 8; ++d) p[d] = acc[j][d];
            p[8] = l[j];
        }
    }
    __syncthreads();
    if (w < 4) {
        #pragma unroll
        for (int j = 0; j < 2; ++j) {
            float* p = &Pm[w][j*64 + t][0];
            #pragma unroll
            for (int d = 0; d < 8; ++d) p[d] += acc[j][d];
            p[8] += l[j];
        }
    }
    __syncthreads();
    if (tid < 128) {
        int i = tid;
        float L = 0.f, o[8] = {};
        #pragma unroll
        for (int v = 0; v < 4; ++v) {
            const float* p = &Pm[v][i][0];
            #pragma unroll
            for (int d = 0; d < 8; ++d) o[d] += p[d];
            L += p[8];
        }
        float inv = 1.0f / L;
        float* dst = &AO[((size_t)b * NTOK + n0 + i) * 64 + 8 * h];
        *(float4*)&dst[0] = make_float4(o[0]*inv, o[1]*inv, o[2]*inv, o[3]*inv);
        *(float4*)&dst[4] = make_float4(o[4]*inv, o[5]*inv, o[6]*inv, o[7]*inv);
    }
}

// Fused 2x K=64 GEMM (W1,W2) + beff + GELU + transposed store.
// grid(72, 2): 32-token tiles x batch. AO rows already normalized fp32.
__global__ __launch_bounds__(256) void outcomp_kernel(
    const float* __restrict__ AOr, const float* __restrict__ AOd,
    const float* __restrict__ W1, const float* __restrict__ W2,
    const float* __restrict__ beff, float* __restrict__ out)
{
    int tile = blockIdx.x;       // 0..71
    int b    = blockIdx.y;
    int n0 = tile * 32;
    __shared__ float Ar[32][68];
    __shared__ float Ad[32][68];
    __shared__ float W1s[64][68];
    __shared__ float W2s[64][68];
    int tid = threadIdx.x;
    #pragma unroll
    for (int pass = 0; pass < 2; ++pass) {
        int idx = tid + pass*256;
        int row = idx >> 4, c4 = (idx & 15) * 4;
        *(float4*)&Ar[row][c4] = *(const float4*)&AOr[((size_t)b*NTOK + n0 + row)*64 + c4];
        *(float4*)&Ad[row][c4] = *(const float4*)&AOd[((size_t)b*NTOK + n0 + row)*64 + c4];
    }
    {
        int sr = tid >> 4, sc4 = (tid & 15) * 4;
        #pragma unroll
        for (int rr = 0; rr < 4; ++rr) {
            int r = rr*16 + sr;
            *(float4*)&W1s[r][sc4] = *(const float4*)&W1[r*64 + sc4];
            *(float4*)&W2s[r][sc4] = *(const float4*)&W2[r*64 + sc4];
        }
    }
    __syncthreads();

    int tx = tid & 15, ty = tid >> 4;
    float g[2][4] = {};
    #pragma unroll
    for (int k = 0; k < 64; k += 4) {
        float4 xr0 = *(const float4*)&Ar[2*ty][k];
        float4 xr1 = *(const float4*)&Ar[2*ty + 1][k];
        float4 xd0 = *(const float4*)&Ad[2*ty][k];
        float4 xd1 = *(const float4*)&Ad[2*ty + 1][k];
        #pragma unroll
        for (int jj = 0; jj < 4; ++jj) {
            float4 w1 = *(const float4*)&W1s[tx + 16*jj][k];
            float4 w2 = *(const float4*)&W2s[tx + 16*jj][k];
            g[0][jj] += xr0.x*w1.x + xr0.y*w1.y + xr0.z*w1.z + xr0.w*w1.w
                      + xd0.x*w2.x + xd0.y*w2.y + xd0.z*w2.z + xd0.w*w2.w;
            g[1][jj] += xr1.x*w1.x + xr1.y*w1.y + xr1.z*w1.z + xr1.w*w1.w
                      + xd1.x*w2.x + xd1.y*w2.y + xd1.z*w2.z + xd1.w*w2.w;
        }
    }
    #pragma unroll
    for (int jj = 0; jj < 4; ++jj) {
        int o = tx + 16*jj;
        float be = beff[o];
        #pragma unroll
        for (int i = 0; i < 2; ++i) {
            int n = n0 + 2*ty + i;
            int wi = n / HH, hi = n % HH;
            float x = g[i][jj] + be;
            float gl = 0.5f * x * (1.0f + erff(x * 0.70710678118654752f));
            out[((b*C + o)*WW + wi)*HH + hi] = gl;
        }
    }
}

// ===========================================================================
// FALLBACK (R9 big path, proven): ws >= 3,538,944 B.
// ===========================================================================
__global__ __launch_bounds__(256) void kv_all_kernel(
    const float* __restrict__ rgb, const float* __restrict__ dep,
    const float* __restrict__ w_exp, const float* __restrict__ b_exp,
    const float* __restrict__ w_rk, const float* __restrict__ w_rv,
    const float* __restrict__ w_dk, const float* __restrict__ w_dv,
    bf16_t* __restrict__ Kr, bf16_t* __restrict__ Vr,
    bf16_t* __restrict__ Kd, bf16_t* __restrict__ Vd)
{
    int tile = blockIdx.x;
    int m    = blockIdx.y;
    int z    = blockIdx.z;
    int b = z >> 1, strm = z & 1;
    const float* W = strm ? (m ? w_dv : w_dk) : (m ? w_rv : w_rk);
    bf16_t* O = (strm ? (m ? Vd : Kd) : (m ? Vr : Kr))
              + ((size_t)b * NTOK + tile * 64) * 64;

    __shared__ float Xs[64][68];
    __shared__ float Ws[64][68];
    int tid = threadIdx.x;
    {
        int r = tid & 63, c0 = tid >> 6;
        stage_x_row(&Xs[r][0], rgb, dep, w_exp, b_exp, b, tile*64 + r, strm, c0, 4);
    }
    int sr = tid >> 4, sc = (tid & 15) * 4;
    #pragma unroll
    for (int rr = 0; rr < 4; ++rr) {
        int r = rr*16 + sr;
        *(float4*)&Ws[r][sc] = *(const float4*)&W[r*64 + sc];
    }
    __syncthreads();

    int ty = tid >> 4, tx = tid & 15;
    float acc[4][4] = {};
    #pragma unroll
    for (int k = 0; k < 64; k += 4) {
        float4 xv[4], wv4[4];
        #pragma unroll
        for (int i = 0; i < 4; ++i) xv[i] = *(const float4*)&Xs[4*ty + i][k];
        #pragma unroll
        for (int j = 0; j < 4; ++j) wv4[j] = *(const float4*)&Ws[tx + 16*j][k];
        #pragma unroll
        for (int i = 0; i < 4; ++i)
            #pragma unroll
            for (int j = 0; j < 4; ++j)
                acc[i][j] += xv[i].x*wv4[j].x + xv[i].y*wv4[j].y + xv[i].z*wv4[j].z + xv[i].w*wv4[j].w;
    }
    #pragma unroll
    for (int i = 0; i < 4; ++i)
        #pragma unroll
        for (int j = 0; j < 4; ++j)
            O[(4*ty + i)*64 + tx + 16*j] = f2bf(acc[i][j]);
}

__global__ __launch_bounds__(256) void attn_all_kernel(
    const float* __restrict__ rgb, const float* __restrict__ dep,
    const float* __restrict__ w_exp, const float* __restrict__ b_exp,
    const float* __restrict__ w_rq, const float* __restrict__ w_dq,
    const bf16_t* __restrict__ Kr, const bf16_t* __restrict__ Vr,
    const bf16_t* __restrict__ Kd, const bf16_t* __restrict__ Vd,
    bf16_t* __restrict__ AOr, bf16_t* __restrict__ AOd)
{
    int qt = blockIdx.x;
    int h  = blockIdx.y;
    int z  = blockIdx.z;
    int b = z >> 1, which = z & 1;
    const float* wq = which ? w_dq : w_rq;
    const bf16_t* K = which ? Kr : Kd;
    const bf16_t* V = which ? Vr : Vd;
    bf16_t* AO      = which ? AOd : AOr;

    __shared__ float Xs[64][68];
    __shared__ float Wqs[8][64];
    __shared__ __align__(16) float Ks[4][64][KVSTRIDE];
    __shared__ __align__(16) float Vs[4][64][KVSTRIDE];

    int tid = threadIdx.x;
    int t = tid & 63;
    int w = tid >> 6;
    int n = qt * 64 + t;

    stage_x_row(&Xs[t][0], rgb, dep, w_exp, b_exp, b, n, which == 0 ? 0 : 1, w, 4);
    if (w == 0) {
        #pragma unroll
        for (int d = 0; d < 8; ++d) Wqs[d][t] = wq[(8*h + d)*64 + t];
    }
    __syncthreads();

    const float sc = 0.35355339059327373f * 1.4426950408889634f;
    float q[8];
    #pragma unroll
    for (int d = 0; d < 8; ++d) {
        float s = 0.f;
        #pragma unroll 8
        for (int c = 0; c < 64; ++c) s += Xs[t][c] * Wqs[d][c];
        q[d] = s * sc;
    }

    float mrun = -INFINITY, l = 0.f;
    float acc[8] = {};

    #pragma unroll 1
    for (int st = 0; st < 9; ++st) {
        __syncthreads();
        {
            size_t g = ((size_t)b * NTOK + (w*576 + st*64 + t)) * 64 + 8 * h;
            *(float4*)&Ks[w][t][0] = ld_bf4(&K[g]);
            *(float4*)&Ks[w][t][4] = ld_bf4(&K[g + 4]);
            *(float4*)&Vs[w][t][0] = ld_bf4(&V[g]);
            *(float4*)&Vs[w][t][4] = ld_bf4(&V[g + 4]);
        }
        __syncthreads();

        for (int g8 = 0; g8 < 8; ++g8) {
            float s[8];
            #pragma unroll
            for (int u = 0; u < 8; ++u) {
                const float4 ka = *(const float4*)&Ks[w][g8*8 + u][0];
                const float4 kb = *(const float4*)&Ks[w][g8*8 + u][4];
                s[u] = q[0]*ka.x + q[1]*ka.y + q[2]*ka.z + q[3]*ka.w
                     + q[4]*kb.x + q[5]*kb.y + q[6]*kb.z + q[7]*kb.w;
            }
            float tm = fmaxf(fmaxf(fmaxf(s[0],s[1]), fmaxf(s[2],s[3])),
                             fmaxf(fmaxf(s[4],s[5]), fmaxf(s[6],s[7])));
            float mn = fmaxf(mrun, tm);
            float alpha = __builtin_amdgcn_exp2f(mrun - mn);
            float ps = 0.f;
            #pragma unroll
            for (int u = 0; u < 8; ++u) { s[u] = __builtin_amdgcn_exp2f(s[u] - mn); ps += s[u]; }
            l = l * alpha + ps;
            #pragma unroll
            for (int d = 0; d < 8; ++d) acc[d] *= alpha;
            #pragma unroll
            for (int u = 0; u < 8; ++u) {
                const float4 va = *(const float4*)&Vs[w][g8*8 + u][0];
                const float4 vb = *(const float4*)&Vs[w][g8*8 + u][4];
                acc[0] += s[u]*va.x; acc[1] += s[u]*va.y; acc[2] += s[u]*va.z; acc[3] += s[u]*va.w;
                acc[4] += s[u]*vb.x; acc[5] += s[u]*vb.y; acc[6] += s[u]*vb.z; acc[7] += s[u]*vb.w;
            }
            mrun = mn;
        }
    }

    float* part = &Xs[0][0];
    __syncthreads();
    {
        float* p = &part[(w*64 + t) * 10];
        p[0] = mrun; p[1] = l;
        #pragma unroll
        for (int d = 0; d < 8; ++d) p[2 + d] = acc[d];
    }
    __syncthreads();
    if (tid < 64) {
        float M = -INFINITY;
        #pragma unroll
        for (int v = 0; v < 4; ++v) M = fmaxf(M, part[(v*64 + t)*10]);
        float L = 0.f, o[8] = {};
        #pragma unroll
        for (int v = 0; v < 4; ++v) {
            const float* p = &part[(v*64 + t)*10];
            float al = __builtin_amdgcn_exp2f(p[0] - M);
            L += p[1] * al;
            #pragma unroll
            for (int d = 0; d < 8; ++d) o[d] += p[2 + d] * al;
        }
        float inv = 1.0f / L;
        uint4 ov;
        ov.x = pack2(o[0]*inv, o[1]*inv);
        ov.y = pack2(o[2]*inv, o[3]*inv);
        ov.z = pack2(o[4]*inv, o[5]*inv);
        ov.w = pack2(o[6]*inv, o[7]*inv);
        *(uint4*)&AO[((size_t)b * NTOK + n) * 64 + 8 * h] = ov;
    }
}

__global__ __launch_bounds__(256) void projcomp_all_kernel(
    const bf16_t* __restrict__ AOr, const bf16_t* __restrict__ AOd,
    const float* __restrict__ w_rp, const float* __restrict__ b_rp,
    const float* __restrict__ w_dp, const float* __restrict__ b_dp,
    const float* __restrict__ w_comp, const float* __restrict__ b_comp,
    float* __restrict__ out)
{
    int tile = blockIdx.x;
    int b    = blockIdx.y;
    __shared__ float A[64][68];
    __shared__ float Bf[64][68];
    __shared__ float Pf[64][68];
    int tid = threadIdx.x;
    int sr = tid >> 4, sc = (tid & 15) * 4;
    int ty = tid >> 4, tx = tid & 15;
    float G[4][4] = {};

    #pragma unroll
    for (int half = 0; half < 2; ++half) {
        const bf16_t* AOx = half ? AOd : AOr;
        const float* Wp   = half ? w_dp : w_rp;
        const float* bp   = half ? b_dp : b_rp;
        #pragma unroll
        for (int rr = 0; rr < 4; ++rr) {
            int r = rr*16 + sr;
            *(float4*)&A[r][sc]  = ld_bf4(&AOx[((size_t)b*NTOK + tile*64 + r)*64 + sc]);
            *(float4*)&Bf[r][sc] = *(const float4*)&Wp[r*64 + sc];
        }
        __syncthreads();
        float acc[4][4] = {};
        #pragma unroll
        for (int k = 0; k < 64; k += 4) {
            float4 xv[4], wv[4];
            #pragma unroll
            for (int i = 0; i < 4; ++i) xv[i] = *(const float4*)&A[4*ty + i][k];
            #pragma unroll
            for (int j = 0; j < 4; ++j) wv[j] = *(const float4*)&Bf[tx + 16*j][k];
            #pragma unroll
            for (int i = 0; i < 4; ++i)
                #pragma unroll
                for (int j = 0; j < 4; ++j)
                    acc[i][j] += xv[i].x*wv[j].x + xv[i].y*wv[j].y + xv[i].z*wv[j].z + xv[i].w*wv[j].w;
        }
        __syncthreads();
        #pragma unroll
        for (int j = 0; j < 4; ++j) {
            float bj = bp[tx + 16*j];
            #pragma unroll
            for (int i = 0; i < 4; ++i)
                Pf[4*ty + i][tx + 16*j] = acc[i][j] + bj;
        }
        #pragma unroll
        for (int rr = 0; rr < 4; ++rr) {
            int r = rr*16 + sr;
            *(float4*)&Bf[r][sc] = *(const float4*)&w_comp[r*128 + half*64 + sc];
        }
        __syncthreads();
        #pragma unroll
        for (int k = 0; k < 64; k += 4) {
            float4 xv[4], wv[4];
            #pragma unroll
            for (int i = 0; i < 4; ++i) xv[i] = *(const float4*)&Pf[4*ty + i][k];
            #pragma unroll
            for (int j = 0; j < 4; ++j) wv[j] = *(const float4*)&Bf[tx + 16*j][k];
            #pragma unroll
            for (int i = 0; i < 4; ++i)
                #pragma unroll
                for (int j = 0; j < 4; ++j)
                    G[i][j] += xv[i].x*wv[j].x + xv[i].y*wv[j].y + xv[i].z*wv[j].z + xv[i].w*wv[j].w;
        }
        __syncthreads();
    }

    #pragma unroll
    for (int j = 0; j < 4; ++j) {
        int o = tx + 16*j;
        float bj = b_comp[o];
        #pragma unroll
        for (int i = 0; i < 4; ++i) {
            int n = tile*64 + 4*ty + i;
            int wi = n / HH, hi = n % HH;
            float x = G[i][j] + bj;
            float g = 0.5f * x * (1.0f + erff(x * 0.70710678118654752f));
            out[((b*C + o)*WW + wi)*HH + hi] = g;
        }
    }
}

// ---------------------------------------------------------------------------
extern "C" void kernel_launch(void* const* d_in, const int* in_sizes, int n_in,
                              void* d_out, int out_size, void* d_ws, size_t ws_size,
                              hipStream_t stream) {
    const float* rgb_fea = (const float*)d_in[0];
    const float* depth   = (const float*)d_in[1];
    const float* w_exp   = (const float*)d_in[2];
    const float* b_exp   = (const float*)d_in[3];
    const float* w_rq    = (const float*)d_in[4];
    const float* w_rk    = (const float*)d_in[5];
    const float* w_rv    = (const float*)d_in[6];
    const float* w_dq    = (const float*)d_in[7];
    const float* w_dk    = (const float*)d_in[8];
    const float* w_dv    = (const float*)d_in[9];
    const float* w_rp    = (const float*)d_in[10];
    const float* b_rp    = (const float*)d_in[11];
    const float* w_dp    = (const float*)d_in[12];
    const float* b_dp    = (const float*)d_in[13];
    const float* w_comp  = (const float*)d_in[14];
    const float* b_comp  = (const float*)d_in[15];
    float* out = (float*)d_out;

    if (ws_size >= 5931264) {
        char* Wb = (char*)d_ws;
        bf16_t* Qb  = (bf16_t*)Wb;                 // [4][8][2304][8] bf16
        bf16_t* Kb  = (bf16_t*)(Wb + 1179648);
        bf16_t* Vb  = (bf16_t*)(Wb + 2359296);
        float* AOr  = (float*)(Wb + 3538944);      // [2][2304][64] fp32
        float* AOd  = (float*)(Wb + 4718592);
        float* W1   = (float*)(Wb + 5898240);
        float* W2   = (float*)(Wb + 5914624);
        float* beff = (float*)(Wb + 5931008);

        wprep_kernel<<<dim3(4, 2), dim3(256), 0, stream>>>(
            w_rp, w_dp, w_comp, b_rp, b_dp, b_comp, W1, W2, beff);
        qkv_kernel<<<dim3(36, 3, 4), dim3(256), 0, stream>>>(
            rgb_fea, depth, w_exp, b_exp,
            w_rq, w_rk, w_rv, w_dq, w_dk, w_dv, Qb, Kb, Vb);
        attn_kernel<<<dim3(18, 8, 4), dim3(512), 0, stream>>>(
            Qb, Kb, Vb, AOr, AOd);
        outcomp_kernel<<<dim3(72, 2), dim3(256), 0, stream>>>(
            AOr, AOd, W1, W2, beff, out);
    } else {
        // R9 big path (proven)
        const size_t BUF = (size_t)BATCH * NTOK * 64;
        bf16_t* Kr  = (bf16_t*)d_ws;
        bf16_t* Vr  = Kr + BUF;
        bf16_t* Kd  = Vr + BUF;
        bf16_t* Vd  = Kd + BUF;
        bf16_t* AOr = Vd + BUF;
        bf16_t* AOd = AOr + BUF;
        kv_all_kernel<<<dim3(36, 2, 4), dim3(256), 0, stream>>>(
            rgb_fea, depth, w_exp, b_exp, w_rk, w_rv, w_dk, w_dv, Kr, Vr, Kd, Vd);
        attn_all_kernel<<<dim3(36, 8, 4), dim3(256), 0, stream>>>(
            rgb_fea, depth, w_exp, b_exp, w_rq, w_dq, Kr, Vr, Kd, Vd, AOr, AOd);
        projcomp_all_kernel<<<dim3(36, 2), dim3(256), 0, stream>>>(
            AOr, AOd, w_rp, b_rp, w_dp, b_dp, w_comp, b_comp, out);
    }
}

// Round 14
// 197.828 us; speedup vs baseline: 2.9234x; 1.4694x over previous
//
#include <hip/hip_runtime.h>
#include <math.h>

// R13: 290us; attn 176us, VALUBusy 67% -> VALU-issue floor ~120us for the
// fp32 pipeline; MfmaUtil 0 the whole session. R14: MFMA flash attention
// (16x16x32 bf16): QK^T K=32 (head dim in quad0, rest zero), exp2+bf16 P via
// per-wave LDS (no barriers), PV with ones-column in V_aug so l comes out of
// the same mfma. V stored transposed (VT[h][d][key]) by qkv. 4608 indep waves.
#define BATCH 2
#define C 64
#define HH 48
#define WW 48
#define NTOK 2304
#define HEADS 8
#define KVSTRIDE 12

typedef unsigned short bf16_t;
typedef __attribute__((ext_vector_type(8))) short bf16x8;
typedef __attribute__((ext_vector_type(4))) float f32x4;

__device__ __forceinline__ bf16_t f2bf(float f) {
    unsigned int u = __float_as_uint(f);
    u = (u + 0x7fffu + ((u >> 16) & 1u)) >> 16;   // RNE
    return (bf16_t)u;
}
__device__ __forceinline__ unsigned pack2(float a, float b) {
    return (unsigned)f2bf(a) | ((unsigned)f2bf(b) << 16);
}
__device__ __forceinline__ float4 ld_bf4(const bf16_t* p) {
    uint2 v = *(const uint2*)p;
    float4 r;
    r.x = __uint_as_float(v.x << 16); r.y = __uint_as_float(v.x & 0xffff0000u);
    r.z = __uint_as_float(v.y << 16); r.w = __uint_as_float(v.y & 0xffff0000u);
    return r;
}

// Stage one token-row of X. strm 0: rgb transpose gather. strm 1: conv1x1+
// ReLU+bilinear x2 (half-pixel; clamp == jax edge renorm for 24->48).
__device__ __forceinline__ void stage_x_row(
    float* xrow, const float* rgb, const float* dep,
    const float* w_exp, const float* b_exp,
    int b, int n, int strm, int c0, int cstep)
{
    int wi = n / HH, hi = n % HH;
    if (strm == 0) {
        const float* base = rgb + (size_t)b * C * NTOK + (size_t)hi * WW + wi;
        for (int c = c0; c < 64; c += cstep)
            xrow[c] = base[(size_t)c * NTOK];
    } else {
        float cy = 0.5f * hi - 0.25f, cx = 0.5f * wi - 0.25f;
        float fy0 = floorf(cy), fx0 = floorf(cx);
        float fy = cy - fy0, fx = cx - fx0;
        int y0 = max((int)fy0, 0), x0 = max((int)fx0, 0);
        int y1 = min((int)fy0 + 1, 23), x1 = min((int)fx0 + 1, 23);
        const float* dp = dep + b * 576;
        float d00 = dp[y0*24 + x0], d01 = dp[y0*24 + x1];
        float d10 = dp[y1*24 + x0], d11 = dp[y1*24 + x1];
        for (int c = c0; c < 64; c += cstep) {
            float w = w_exp[c], bb = b_exp[c];
            float r00 = fmaxf(w*d00 + bb, 0.f), r01 = fmaxf(w*d01 + bb, 0.f);
            float r10 = fmaxf(w*d10 + bb, 0.f), r11 = fmaxf(w*d11 + bb, 0.f);
            xrow[c] = (1.f-fy)*((1.f-fx)*r00 + fx*r01) + fy*((1.f-fx)*r10 + fx*r11);
        }
    }
}

// ===========================================================================
// MAIN PATH (ws >= 5,931,264 B)
// ===========================================================================

// W1 = Wc[:, :64] @ Wrp ; W2 = Wc[:, 64:] @ Wdp ; beff = Wc@[br;bd] + bc.
__global__ __launch_bounds__(256) void wprep_kernel(
    const float* __restrict__ w_rp, const float* __restrict__ w_dp,
    const float* __restrict__ w_comp,
    const float* __restrict__ b_rp, const float* __restrict__ b_dp,
    const float* __restrict__ b_comp,
    float* __restrict__ W1, float* __restrict__ W2, float* __restrict__ beff)
{
    int bx = blockIdx.x, m = blockIdx.y;
    const float* Wp = m ? w_dp : w_rp;
    float* Wo = m ? W2 : W1;
    __shared__ float Wps[64][68];
    int tid = threadIdx.x;
    int sr = tid >> 4, sc4 = (tid & 15) * 4;
    #pragma unroll
    for (int rr = 0; rr < 4; ++rr) {
        int r = rr*16 + sr;
        *(float4*)&Wps[r][sc4] = *(const float4*)&Wp[r*64 + sc4];
    }
    __syncthreads();
    int r = tid >> 4;
    int o = bx*16 + r;
    int c4 = (tid & 15) * 4;
    float a0 = 0, a1 = 0, a2 = 0, a3 = 0;
    for (int j = 0; j < 64; ++j) {
        float wc = w_comp[o*128 + m*64 + j];
        float4 wp = *(const float4*)&Wps[j][c4];
        a0 += wc*wp.x; a1 += wc*wp.y; a2 += wc*wp.z; a3 += wc*wp.w;
    }
    Wo[o*64 + c4]     = a0;
    Wo[o*64 + c4 + 1] = a1;
    Wo[o*64 + c4 + 2] = a2;
    Wo[o*64 + c4 + 3] = a3;
    if (bx == 0 && m == 0 && tid < 64) {
        float s = b_comp[tid];
        for (int j = 0; j < 64; ++j)
            s += w_comp[tid*128 + j] * b_rp[j] + w_comp[tid*128 + 64 + j] * b_dp[j];
        beff[tid] = s;
    }
}

// prep + one of {Q,K,V} GEMM per (b,strm). grid(36, 3, 4), 256 thr.
// Q,K -> [sb][h][n][8] bf16 (Q pre-scaled by 8^-0.5*log2e).
// V -> TRANSPOSED [sb][h][d][n] bf16 (for MFMA B-fragment loads).
__global__ __launch_bounds__(256) void qkv_kernel(
    const float* __restrict__ rgb, const float* __restrict__ dep,
    const float* __restrict__ w_exp, const float* __restrict__ b_exp,
    const float* __restrict__ w_rq, const float* __restrict__ w_rk, const float* __restrict__ w_rv,
    const float* __restrict__ w_dq, const float* __restrict__ w_dk, const float* __restrict__ w_dv,
    bf16_t* __restrict__ Qb, bf16_t* __restrict__ Kb, bf16_t* __restrict__ VT)
{
    int tile = blockIdx.x;
    int m    = blockIdx.y;
    int z    = blockIdx.z;
    int b = z >> 1, strm = z & 1;
    const float* W = strm ? (m == 0 ? w_dq : m == 1 ? w_dk : w_dv)
                          : (m == 0 ? w_rq : m == 1 ? w_rk : w_rv);
    int sb = strm*2 + b;
    float scale = (m == 0) ? (0.35355339059327373f * 1.4426950408889634f) : 1.0f;

    __shared__ float Xs[64][68];
    __shared__ float Ws[64][68];
    int tid = threadIdx.x;
    {
        int r = tid & 63, c0 = tid >> 6;
        stage_x_row(&Xs[r][0], rgb, dep, w_exp, b_exp, b, tile*64 + r, strm, c0, 4);
    }
    int sr = tid >> 4, sc = (tid & 15) * 4;
    #pragma unroll
    for (int rr = 0; rr < 4; ++rr) {
        int r = rr*16 + sr;
        *(float4*)&Ws[r][sc] = *(const float4*)&W[r*64 + sc];
    }
    __syncthreads();

    int ty = tid >> 4, tx = tid & 15;
    float acc[4][4] = {};
    #pragma unroll
    for (int k = 0; k < 64; k += 4) {
        float4 xv[4], wv4[4];
        #pragma unroll
        for (int i = 0; i < 4; ++i) xv[i] = *(const float4*)&Xs[4*ty + i][k];
        #pragma unroll
        for (int j = 0; j < 4; ++j) wv4[j] = *(const float4*)&Ws[tx + 16*j][k];
        #pragma unroll
        for (int i = 0; i < 4; ++i)
            #pragma unroll
            for (int j = 0; j < 4; ++j)
                acc[i][j] += xv[i].x*wv4[j].x + xv[i].y*wv4[j].y + xv[i].z*wv4[j].z + xv[i].w*wv4[j].w;
    }
    #pragma unroll
    for (int j = 0; j < 4; ++j) {
        int o = tx + 16*j;
        int h = o >> 3, d = o & 7;
        #pragma unroll
        for (int i = 0; i < 4; ++i) {
            int n = tile*64 + 4*ty + i;
            bf16_t v = f2bf(acc[i][j] * scale);
            if (m == 0)      Qb[(((size_t)sb*8 + h)*NTOK + n)*8 + d] = v;
            else if (m == 1) Kb[(((size_t)sb*8 + h)*NTOK + n)*8 + d] = v;
            else             VT[(((size_t)sb*8 + h)*8 + d)*NTOK + n] = v;
        }
    }
}

// MFMA flash attention. grid(36, 8, 4): qt-group x head x (b*2+which).
// 256 thr = 4 INDEPENDENT waves (no __syncthreads); wave w handles qtile
// blockIdx.x*4+w = 16 queries, looping 72 chunks of 32 keys:
//   S(16x32) = 2x mfma_16x16x32 (head dim in quad0, quads1-3 zero)
//   P = exp2(S) (no-max; proven) -> bf16 trunc -> per-wave LDS -> A-frag
//   O_aug(16x16) += P x V_aug  (V dims at n<8, ONES at n=8 -> l in col 8)
// AO stored normalized fp32 [b][n][64].
__global__ __launch_bounds__(256) void attn_kernel(
    const bf16_t* __restrict__ Qb, const bf16_t* __restrict__ Kb,
    const bf16_t* __restrict__ VT,
    float* __restrict__ AOr, float* __restrict__ AOd)
{
    int h = blockIdx.y;
    int z = blockIdx.z;
    int b = z >> 1, which = z & 1;
    int qsb = which * 2 + b;
    int ksb = (1 - which) * 2 + b;
    const bf16_t* Q  = Qb + ((size_t)qsb * 8 + h) * NTOK * 8;
    const bf16_t* K  = Kb + ((size_t)ksb * 8 + h) * NTOK * 8;
    const bf16_t* Vt = VT + ((size_t)ksb * 8 + h) * 8 * NTOK;  // [d][key]
    float* AO = which ? AOd : AOr;

    __shared__ __align__(16) bf16_t Pls[4][16][32];  // per-wave P tiles (4 KB)
    __shared__ __align__(16) float  Ols[4][16][16];  // per-wave O tiles (4 KB)

    int tid = threadIdx.x;
    int t = tid & 63, w = tid >> 6;
    int m16 = t & 15, quad = t >> 4;
    int qt = blockIdx.x * 4 + w;       // 0..143
    int n0 = qt * 16;

    const bf16x8 zf = {0,0,0,0,0,0,0,0};
    const bf16x8 onesf = {0x3F80,0x3F80,0x3F80,0x3F80,0x3F80,0x3F80,0x3F80,0x3F80};
    const f32x4 cz = {0.f, 0.f, 0.f, 0.f};

    // Q fragment: A[m=lane&15][k=quad*8+j]; only quad 0 (dims 0-7) real.
    bf16x8 qf = (quad == 0) ? *(const bf16x8*)&Q[(size_t)(n0 + m16) * 8] : zf;

    f32x4 oacc = cz;

    #pragma unroll 1
    for (int ck = 0; ck < 72; ++ck) {
        int k0 = ck * 32;
        // K fragments (B[n=key][k=dim], quad0 real): keys k0+m16, k0+16+m16
        bf16x8 kf0 = (quad == 0) ? *(const bf16x8*)&K[(size_t)(k0 + m16) * 8]      : zf;
        bf16x8 kf1 = (quad == 0) ? *(const bf16x8*)&K[(size_t)(k0 + 16 + m16) * 8] : zf;
        // V_aug fragment (B[n=dim][k=key]): n<8 -> VT row, n==8 -> ones, else 0
        bf16x8 vf = (m16 < 8) ? *(const bf16x8*)&Vt[(size_t)m16 * NTOK + k0 + quad * 8]
                  : (m16 == 8 ? onesf : zf);

        f32x4 s0 = __builtin_amdgcn_mfma_f32_16x16x32_bf16(qf, kf0, cz, 0, 0, 0);
        f32x4 s1 = __builtin_amdgcn_mfma_f32_16x16x32_bf16(qf, kf1, cz, 0, 0, 0);

        // exp2 + bf16-truncate -> P[row=quad*4+r][col]; wave-synchronous LDS
        #pragma unroll
        for (int r = 0; r < 4; ++r) {
            float p0 = __builtin_amdgcn_exp2f(s0[r]);
            float p1 = __builtin_amdgcn_exp2f(s1[r]);
            Pls[w][quad*4 + r][m16]      = (bf16_t)(__float_as_uint(p0) >> 16);
            Pls[w][quad*4 + r][m16 + 16] = (bf16_t)(__float_as_uint(p1) >> 16);
        }
        // P as A-fragment: A[m=lane&15][k=quad*8+j] -> contiguous b128
        bf16x8 pf = *(const bf16x8*)&Pls[w][m16][quad * 8];
        oacc = __builtin_amdgcn_mfma_f32_16x16x32_bf16(pf, vf, oacc, 0, 0, 0);
    }

    // epilogue: O C-frag -> LDS; col 8 holds l; normalize and store.
    #pragma unroll
    for (int r = 0; r < 4; ++r)
        Ols[w][quad*4 + r][m16] = oacc[r];
    #pragma unroll
    for (int e = 0; e < 2; ++e) {
        int idx = t * 2 + e;           // 0..127 = 16 q x 8 d
        int qq = idx >> 3, d = idx & 7;
        float val = Ols[w][qq][d] / Ols[w][qq][8];
        AO[((size_t)b * NTOK + n0 + qq) * 64 + 8 * h + d] = val;
    }
}

// Fused 2x K=64 GEMM (W1,W2) + beff + GELU + transposed store.
// grid(72, 2): 32-token tiles x batch. AO rows already normalized fp32.
__global__ __launch_bounds__(256) void outcomp_kernel(
    const float* __restrict__ AOr, const float* __restrict__ AOd,
    const float* __restrict__ W1, const float* __restrict__ W2,
    const float* __restrict__ beff, float* __restrict__ out)
{
    int tile = blockIdx.x;       // 0..71
    int b    = blockIdx.y;
    int n0 = tile * 32;
    __shared__ float Ar[32][68];
    __shared__ float Ad[32][68];
    __shared__ float W1s[64][68];
    __shared__ float W2s[64][68];
    int tid = threadIdx.x;
    #pragma unroll
    for (int pass = 0; pass < 2; ++pass) {
        int idx = tid + pass*256;
        int row = idx >> 4, c4 = (idx & 15) * 4;
        *(float4*)&Ar[row][c4] = *(const float4*)&AOr[((size_t)b*NTOK + n0 + row)*64 + c4];
        *(float4*)&Ad[row][c4] = *(const float4*)&AOd[((size_t)b*NTOK + n0 + row)*64 + c4];
    }
    {
        int sr = tid >> 4, sc4 = (tid & 15) * 4;
        #pragma unroll
        for (int rr = 0; rr < 4; ++rr) {
            int r = rr*16 + sr;
            *(float4*)&W1s[r][sc4] = *(const float4*)&W1[r*64 + sc4];
            *(float4*)&W2s[r][sc4] = *(const float4*)&W2[r*64 + sc4];
        }
    }
    __syncthreads();

    int tx = tid & 15, ty = tid >> 4;
    float g[2][4] = {};
    #pragma unroll
    for (int k = 0; k < 64; k += 4) {
        float4 xr0 = *(const float4*)&Ar[2*ty][k];
        float4 xr1 = *(const float4*)&Ar[2*ty + 1][k];
        float4 xd0 = *(const float4*)&Ad[2*ty][k];
        float4 xd1 = *(const float4*)&Ad[2*ty + 1][k];
        #pragma unroll
        for (int jj = 0; jj < 4; ++jj) {
            float4 w1 = *(const float4*)&W1s[tx + 16*jj][k];
            float4 w2 = *(const float4*)&W2s[tx + 16*jj][k];
            g[0][jj] += xr0.x*w1.x + xr0.y*w1.y + xr0.z*w1.z + xr0.w*w1.w
                      + xd0.x*w2.x + xd0.y*w2.y + xd0.z*w2.z + xd0.w*w2.w;
            g[1][jj] += xr1.x*w1.x + xr1.y*w1.y + xr1.z*w1.z + xr1.w*w1.w
                      + xd1.x*w2.x + xd1.y*w2.y + xd1.z*w2.z + xd1.w*w2.w;
        }
    }
    #pragma unroll
    for (int jj = 0; jj < 4; ++jj) {
        int o = tx + 16*jj;
        float be = beff[o];
        #pragma unroll
        for (int i = 0; i < 2; ++i) {
            int n = n0 + 2*ty + i;
            int wi = n / HH, hi = n % HH;
            float x = g[i][jj] + be;
            float gl = 0.5f * x * (1.0f + erff(x * 0.70710678118654752f));
            out[((b*C + o)*WW + wi)*HH + hi] = gl;
        }
    }
}

// ===========================================================================
// FALLBACK (R9 big path, proven): ws >= 3,538,944 B.
// ===========================================================================
__global__ __launch_bounds__(256) void kv_all_kernel(
    const float* __restrict__ rgb, const float* __restrict__ dep,
    const float* __restrict__ w_exp, const float* __restrict__ b_exp,
    const float* __restrict__ w_rk, const float* __restrict__ w_rv,
    const float* __restrict__ w_dk, const float* __restrict__ w_dv,
    bf16_t* __restrict__ Kr, bf16_t* __restrict__ Vr,
    bf16_t* __restrict__ Kd, bf16_t* __restrict__ Vd)
{
    int tile = blockIdx.x;
    int m    = blockIdx.y;
    int z    = blockIdx.z;
    int b = z >> 1, strm = z & 1;
    const float* W = strm ? (m ? w_dv : w_dk) : (m ? w_rv : w_rk);
    bf16_t* O = (strm ? (m ? Vd : Kd) : (m ? Vr : Kr))
              + ((size_t)b * NTOK + tile * 64) * 64;

    __shared__ float Xs[64][68];
    __shared__ float Ws[64][68];
    int tid = threadIdx.x;
    {
        int r = tid & 63, c0 = tid >> 6;
        stage_x_row(&Xs[r][0], rgb, dep, w_exp, b_exp, b, tile*64 + r, strm, c0, 4);
    }
    int sr = tid >> 4, sc = (tid & 15) * 4;
    #pragma unroll
    for (int rr = 0; rr < 4; ++rr) {
        int r = rr*16 + sr;
        *(float4*)&Ws[r][sc] = *(const float4*)&W[r*64 + sc];
    }
    __syncthreads();

    int ty = tid >> 4, tx = tid & 15;
    float acc[4][4] = {};
    #pragma unroll
    for (int k = 0; k < 64; k += 4) {
        float4 xv[4], wv4[4];
        #pragma unroll
        for (int i = 0; i < 4; ++i) xv[i] = *(const float4*)&Xs[4*ty + i][k];
        #pragma unroll
        for (int j = 0; j < 4; ++j) wv4[j] = *(const float4*)&Ws[tx + 16*j][k];
        #pragma unroll
        for (int i = 0; i < 4; ++i)
            #pragma unroll
            for (int j = 0; j < 4; ++j)
                acc[i][j] += xv[i].x*wv4[j].x + xv[i].y*wv4[j].y + xv[i].z*wv4[j].z + xv[i].w*wv4[j].w;
    }
    #pragma unroll
    for (int i = 0; i < 4; ++i)
        #pragma unroll
        for (int j = 0; j < 4; ++j)
            O[(4*ty + i)*64 + tx + 16*j] = f2bf(acc[i][j]);
}

__global__ __launch_bounds__(256) void attn_all_kernel(
    const float* __restrict__ rgb, const float* __restrict__ dep,
    const float* __restrict__ w_exp, const float* __restrict__ b_exp,
    const float* __restrict__ w_rq, const float* __restrict__ w_dq,
    const bf16_t* __restrict__ Kr, const bf16_t* __restrict__ Vr,
    const bf16_t* __restrict__ Kd, const bf16_t* __restrict__ Vd,
    bf16_t* __restrict__ AOr, bf16_t* __restrict__ AOd)
{
    int qt = blockIdx.x;
    int h  = blockIdx.y;
    int z  = blockIdx.z;
    int b = z >> 1, which = z & 1;
    const float* wq = which ? w_dq : w_rq;
    const bf16_t* K = which ? Kr : Kd;
    const bf16_t* V = which ? Vr : Vd;
    bf16_t* AO      = which ? AOd : AOr;

    __shared__ float Xs[64][68];
    __shared__ float Wqs[8][64];
    __shared__ __align__(16) float Ks[4][64][KVSTRIDE];
    __shared__ __align__(16) float Vs[4][64][KVSTRIDE];

    int tid = threadIdx.x;
    int t = tid & 63;
    int w = tid >> 6;
    int n = qt * 64 + t;

    stage_x_row(&Xs[t][0], rgb, dep, w_exp, b_exp, b, n, which == 0 ? 0 : 1, w, 4);
    if (w == 0) {
        #pragma unroll
        for (int d = 0; d < 8; ++d) Wqs[d][t] = wq[(8*h + d)*64 + t];
    }
    __syncthreads();

    const float sc = 0.35355339059327373f * 1.4426950408889634f;
    float q[8];
    #pragma unroll
    for (int d = 0; d < 8; ++d) {
        float s = 0.f;
        #pragma unroll 8
        for (int c = 0; c < 64; ++c) s += Xs[t][c] * Wqs[d][c];
        q[d] = s * sc;
    }

    float mrun = -INFINITY, l = 0.f;
    float acc[8] = {};

    #pragma unroll 1
    for (int st = 0; st < 9; ++st) {
        __syncthreads();
        {
            size_t g = ((size_t)b * NTOK + (w*576 + st*64 + t)) * 64 + 8 * h;
            *(float4*)&Ks[w][t][0] = ld_bf4(&K[g]);
            *(float4*)&Ks[w][t][4] = ld_bf4(&K[g + 4]);
            *(float4*)&Vs[w][t][0] = ld_bf4(&V[g]);
            *(float4*)&Vs[w][t][4] = ld_bf4(&V[g + 4]);
        }
        __syncthreads();

        for (int g8 = 0; g8 < 8; ++g8) {
            float s[8];
            #pragma unroll
            for (int u = 0; u < 8; ++u) {
                const float4 ka = *(const float4*)&Ks[w][g8*8 + u][0];
                const float4 kb = *(const float4*)&Ks[w][g8*8 + u][4];
                s[u] = q[0]*ka.x + q[1]*ka.y + q[2]*ka.z + q[3]*ka.w
                     + q[4]*kb.x + q[5]*kb.y + q[6]*kb.z + q[7]*kb.w;
            }
            float tm = fmaxf(fmaxf(fmaxf(s[0],s[1]), fmaxf(s[2],s[3])),
                             fmaxf(fmaxf(s[4],s[5]), fmaxf(s[6],s[7])));
            float mn = fmaxf(mrun, tm);
            float alpha = __builtin_amdgcn_exp2f(mrun - mn);
            float ps = 0.f;
            #pragma unroll
            for (int u = 0; u < 8; ++u) { s[u] = __builtin_amdgcn_exp2f(s[u] - mn); ps += s[u]; }
            l = l * alpha + ps;
            #pragma unroll
            for (int d = 0; d < 8; ++d) acc[d] *= alpha;
            #pragma unroll
            for (int u = 0; u < 8; ++u) {
                const float4 va = *(const float4*)&Vs[w][g8*8 + u][0];
                const float4 vb = *(const float4*)&Vs[w][g8*8 + u][4];
                acc[0] += s[u]*va.x; acc[1] += s[u]*va.y; acc[2] += s[u]*va.z; acc[3] += s[u]*va.w;
                acc[4] += s[u]*vb.x; acc[5] += s[u]*vb.y; acc[6] += s[u]*vb.z; acc[7] += s[u]*vb.w;
            }
            mrun = mn;
        }
    }

    float* part = &Xs[0][0];
    __syncthreads();
    {
        float* p = &part[(w*64 + t) * 10];
        p[0] = mrun; p[1] = l;
        #pragma unroll
        for (int d = 0; d < 8; ++d) p[2 + d] = acc[d];
    }
    __syncthreads();
    if (tid < 64) {
        float M = -INFINITY;
        #pragma unroll
        for (int v = 0; v < 4; ++v) M = fmaxf(M, part[(v*64 + t)*10]);
        float L = 0.f, o[8] = {};
        #pragma unroll
        for (int v = 0; v < 4; ++v) {
            const float* p = &part[(v*64 + t)*10];
            float al = __builtin_amdgcn_exp2f(p[0] - M);
            L += p[1] * al;
            #pragma unroll
            for (int d = 0; d < 8; ++d) o[d] += p[2 + d] * al;
        }
        float inv = 1.0f / L;
        uint4 ov;
        ov.x = pack2(o[0]*inv, o[1]*inv);
        ov.y = pack2(o[2]*inv, o[3]*inv);
        ov.z = pack2(o[4]*inv, o[5]*inv);
        ov.w = pack2(o[6]*inv, o[7]*inv);
        *(uint4*)&AO[((size_t)b * NTOK + n) * 64 + 8 * h] = ov;
    }
}

__global__ __launch_bounds__(256) void projcomp_all_kernel(
    const bf16_t* __restrict__ AOr, const bf16_t* __restrict__ AOd,
    const float* __restrict__ w_rp, const float* __restrict__ b_rp,
    const float* __restrict__ w_dp, const float* __restrict__ b_dp,
    const float* __restrict__ w_comp, const float* __restrict__ b_comp,
    float* __restrict__ out)
{
    int tile = blockIdx.x;
    int b    = blockIdx.y;
    __shared__ float A[64][68];
    __shared__ float Bf[64][68];
    __shared__ float Pf[64][68];
    int tid = threadIdx.x;
    int sr = tid >> 4, sc = (tid & 15) * 4;
    int ty = tid >> 4, tx = tid & 15;
    float G[4][4] = {};

    #pragma unroll
    for (int half = 0; half < 2; ++half) {
        const bf16_t* AOx = half ? AOd : AOr;
        const float* Wp   = half ? w_dp : w_rp;
        const float* bp   = half ? b_dp : b_rp;
        #pragma unroll
        for (int rr = 0; rr < 4; ++rr) {
            int r = rr*16 + sr;
            *(float4*)&A[r][sc]  = ld_bf4(&AOx[((size_t)b*NTOK + tile*64 + r)*64 + sc]);
            *(float4*)&Bf[r][sc] = *(const float4*)&Wp[r*64 + sc];
        }
        __syncthreads();
        float acc[4][4] = {};
        #pragma unroll
        for (int k = 0; k < 64; k += 4) {
            float4 xv[4], wv[4];
            #pragma unroll
            for (int i = 0; i < 4; ++i) xv[i] = *(const float4*)&A[4*ty + i][k];
            #pragma unroll
            for (int j = 0; j < 4; ++j) wv[j] = *(const float4*)&Bf[tx + 16*j][k];
            #pragma unroll
            for (int i = 0; i < 4; ++i)
                #pragma unroll
                for (int j = 0; j < 4; ++j)
                    acc[i][j] += xv[i].x*wv[j].x + xv[i].y*wv[j].y + xv[i].z*wv[j].z + xv[i].w*wv[j].w;
        }
        __syncthreads();
        #pragma unroll
        for (int j = 0; j < 4; ++j) {
            float bj = bp[tx + 16*j];
            #pragma unroll
            for (int i = 0; i < 4; ++i)
                Pf[4*ty + i][tx + 16*j] = acc[i][j] + bj;
        }
        #pragma unroll
        for (int rr = 0; rr < 4; ++rr) {
            int r = rr*16 + sr;
            *(float4*)&Bf[r][sc] = *(const float4*)&w_comp[r*128 + half*64 + sc];
        }
        __syncthreads();
        #pragma unroll
        for (int k = 0; k < 64; k += 4) {
            float4 xv[4], wv[4];
            #pragma unroll
            for (int i = 0; i < 4; ++i) xv[i] = *(const float4*)&Pf[4*ty + i][k];
            #pragma unroll
            for (int j = 0; j < 4; ++j) wv[j] = *(const float4*)&Bf[tx + 16*j][k];
            #pragma unroll
            for (int i = 0; i < 4; ++i)
                #pragma unroll
                for (int j = 0; j < 4; ++j)
                    G[i][j] += xv[i].x*wv[j].x + xv[i].y*wv[j].y + xv[i].z*wv[j].z + xv[i].w*wv[j].w;
        }
        __syncthreads();
    }

    #pragma unroll
    for (int j = 0; j < 4; ++j) {
        int o = tx + 16*j;
        float bj = b_comp[o];
        #pragma unroll
        for (int i = 0; i < 4; ++i) {
            int n = tile*64 + 4*ty + i;
            int wi = n / HH, hi = n % HH;
            float x = G[i][j] + bj;
            float g = 0.5f * x * (1.0f + erff(x * 0.70710678118654752f));
            out[((b*C + o)*WW + wi)*HH + hi] = g;
        }
    }
}

// ---------------------------------------------------------------------------
extern "C" void kernel_launch(void* const* d_in, const int* in_sizes, int n_in,
                              void* d_out, int out_size, void* d_ws, size_t ws_size,
                              hipStream_t stream) {
    const float* rgb_fea = (const float*)d_in[0];
    const float* depth   = (const float*)d_in[1];
    const float* w_exp   = (const float*)d_in[2];
    const float* b_exp   = (const float*)d_in[3];
    const float* w_rq    = (const float*)d_in[4];
    const float* w_rk    = (const float*)d_in[5];
    const float* w_rv    = (const float*)d_in[6];
    const float* w_dq    = (const float*)d_in[7];
    const float* w_dk    = (const float*)d_in[8];
    const float* w_dv    = (const float*)d_in[9];
    const float* w_rp    = (const float*)d_in[10];
    const float* b_rp    = (const float*)d_in[11];
    const float* w_dp    = (const float*)d_in[12];
    const float* b_dp    = (const float*)d_in[13];
    const float* w_comp  = (const float*)d_in[14];
    const float* b_comp  = (const float*)d_in[15];
    float* out = (float*)d_out;

    if (ws_size >= 5931264) {
        char* Wb = (char*)d_ws;
        bf16_t* Qb  = (bf16_t*)Wb;                 // [4][8][2304][8] bf16
        bf16_t* Kb  = (bf16_t*)(Wb + 1179648);     // [4][8][2304][8] bf16
        bf16_t* VT  = (bf16_t*)(Wb + 2359296);     // [4][8][8][2304] bf16
        float* AOr  = (float*)(Wb + 3538944);      // [2][2304][64] fp32
        float* AOd  = (float*)(Wb + 4718592);
        float* W1   = (float*)(Wb + 5898240);
        float* W2   = (float*)(Wb + 5914624);
        float* beff = (float*)(Wb + 5931008);

        wprep_kernel<<<dim3(4, 2), dim3(256), 0, stream>>>(
            w_rp, w_dp, w_comp, b_rp, b_dp, b_comp, W1, W2, beff);
        qkv_kernel<<<dim3(36, 3, 4), dim3(256), 0, stream>>>(
            rgb_fea, depth, w_exp, b_exp,
            w_rq, w_rk, w_rv, w_dq, w_dk, w_dv, Qb, Kb, VT);
        attn_kernel<<<dim3(36, 8, 4), dim3(256), 0, stream>>>(
            Qb, Kb, VT, AOr, AOd);
        outcomp_kernel<<<dim3(72, 2), dim3(256), 0, stream>>>(
            AOr, AOd, W1, W2, beff, out);
    } else {
        // R9 big path (proven)
        const size_t BUF = (size_t)BATCH * NTOK * 64;
        bf16_t* Kr  = (bf16_t*)d_ws;
        bf16_t* Vr  = Kr + BUF;
        bf16_t* Kd  = Vr + BUF;
        bf16_t* Vd  = Kd + BUF;
        bf16_t* AOr = Vd + BUF;
        bf16_t* AOd = AOr + BUF;
        kv_all_kernel<<<dim3(36, 2, 4), dim3(256), 0, stream>>>(
            rgb_fea, depth, w_exp, b_exp, w_rk, w_rv, w_dk, w_dv, Kr, Vr, Kd, Vd);
        attn_all_kernel<<<dim3(36, 8, 4), dim3(256), 0, stream>>>(
            rgb_fea, depth, w_exp, b_exp, w_rq, w_dq, Kr, Vr, Kd, Vd, AOr, AOd);
        projcomp_all_kernel<<<dim3(36, 2), dim3(256), 0, stream>>>(
            AOr, AOd, w_rp, b_rp, w_dp, b_dp, w_comp, b_comp, out);
    }
}

// Round 15
// 189.091 us; speedup vs baseline: 3.0585x; 1.0462x over previous
//
#include <hip/hip_runtime.h>
#include <math.h>

// R14: 198us; attn 53us (MFMA works, MfmaUtil 11.5%) but 6.7M LDS conflicts
// from Pls b128 reads at 64B row stride (8-way). Residual ~145us: qkv gathers
// X 3x (one block per m). R15: (a) Pls row stride 32->40 bf16 (80B) -> 2-way
// free; (b) qkv fuses Q/K/V into one block (X staged once), grid(36,4).
#define BATCH 2
#define C 64
#define HH 48
#define WW 48
#define NTOK 2304
#define HEADS 8
#define KVSTRIDE 12

typedef unsigned short bf16_t;
typedef __attribute__((ext_vector_type(8))) short bf16x8;
typedef __attribute__((ext_vector_type(4))) float f32x4;

__device__ __forceinline__ bf16_t f2bf(float f) {
    unsigned int u = __float_as_uint(f);
    u = (u + 0x7fffu + ((u >> 16) & 1u)) >> 16;   // RNE
    return (bf16_t)u;
}
__device__ __forceinline__ unsigned pack2(float a, float b) {
    return (unsigned)f2bf(a) | ((unsigned)f2bf(b) << 16);
}
__device__ __forceinline__ float4 ld_bf4(const bf16_t* p) {
    uint2 v = *(const uint2*)p;
    float4 r;
    r.x = __uint_as_float(v.x << 16); r.y = __uint_as_float(v.x & 0xffff0000u);
    r.z = __uint_as_float(v.y << 16); r.w = __uint_as_float(v.y & 0xffff0000u);
    return r;
}

// Stage one token-row of X. strm 0: rgb transpose gather. strm 1: conv1x1+
// ReLU+bilinear x2 (half-pixel; clamp == jax edge renorm for 24->48).
__device__ __forceinline__ void stage_x_row(
    float* xrow, const float* rgb, const float* dep,
    const float* w_exp, const float* b_exp,
    int b, int n, int strm, int c0, int cstep)
{
    int wi = n / HH, hi = n % HH;
    if (strm == 0) {
        const float* base = rgb + (size_t)b * C * NTOK + (size_t)hi * WW + wi;
        for (int c = c0; c < 64; c += cstep)
            xrow[c] = base[(size_t)c * NTOK];
    } else {
        float cy = 0.5f * hi - 0.25f, cx = 0.5f * wi - 0.25f;
        float fy0 = floorf(cy), fx0 = floorf(cx);
        float fy = cy - fy0, fx = cx - fx0;
        int y0 = max((int)fy0, 0), x0 = max((int)fx0, 0);
        int y1 = min((int)fy0 + 1, 23), x1 = min((int)fx0 + 1, 23);
        const float* dp = dep + b * 576;
        float d00 = dp[y0*24 + x0], d01 = dp[y0*24 + x1];
        float d10 = dp[y1*24 + x0], d11 = dp[y1*24 + x1];
        for (int c = c0; c < 64; c += cstep) {
            float w = w_exp[c], bb = b_exp[c];
            float r00 = fmaxf(w*d00 + bb, 0.f), r01 = fmaxf(w*d01 + bb, 0.f);
            float r10 = fmaxf(w*d10 + bb, 0.f), r11 = fmaxf(w*d11 + bb, 0.f);
            xrow[c] = (1.f-fy)*((1.f-fx)*r00 + fx*r01) + fy*((1.f-fx)*r10 + fx*r11);
        }
    }
}

// ===========================================================================
// MAIN PATH (ws >= 5,931,264 B)
// ===========================================================================

// W1 = Wc[:, :64] @ Wrp ; W2 = Wc[:, 64:] @ Wdp ; beff = Wc@[br;bd] + bc.
__global__ __launch_bounds__(256) void wprep_kernel(
    const float* __restrict__ w_rp, const float* __restrict__ w_dp,
    const float* __restrict__ w_comp,
    const float* __restrict__ b_rp, const float* __restrict__ b_dp,
    const float* __restrict__ b_comp,
    float* __restrict__ W1, float* __restrict__ W2, float* __restrict__ beff)
{
    int bx = blockIdx.x, m = blockIdx.y;
    const float* Wp = m ? w_dp : w_rp;
    float* Wo = m ? W2 : W1;
    __shared__ float Wps[64][68];
    int tid = threadIdx.x;
    int sr = tid >> 4, sc4 = (tid & 15) * 4;
    #pragma unroll
    for (int rr = 0; rr < 4; ++rr) {
        int r = rr*16 + sr;
        *(float4*)&Wps[r][sc4] = *(const float4*)&Wp[r*64 + sc4];
    }
    __syncthreads();
    int r = tid >> 4;
    int o = bx*16 + r;
    int c4 = (tid & 15) * 4;
    float a0 = 0, a1 = 0, a2 = 0, a3 = 0;
    for (int j = 0; j < 64; ++j) {
        float wc = w_comp[o*128 + m*64 + j];
        float4 wp = *(const float4*)&Wps[j][c4];
        a0 += wc*wp.x; a1 += wc*wp.y; a2 += wc*wp.z; a3 += wc*wp.w;
    }
    Wo[o*64 + c4]     = a0;
    Wo[o*64 + c4 + 1] = a1;
    Wo[o*64 + c4 + 2] = a2;
    Wo[o*64 + c4 + 3] = a3;
    if (bx == 0 && m == 0 && tid < 64) {
        float s = b_comp[tid];
        for (int j = 0; j < 64; ++j)
            s += w_comp[tid*128 + j] * b_rp[j] + w_comp[tid*128 + 64 + j] * b_dp[j];
        beff[tid] = s;
    }
}

// Fused prep + Q,K,V GEMMs per (b,strm). grid(36, 4), 256 thr. X staged ONCE.
// Q,K -> [sb][h][n][8] bf16 (Q pre-scaled); V -> TRANSPOSED [sb][h][d][n].
__global__ __launch_bounds__(256) void qkv_kernel(
    const float* __restrict__ rgb, const float* __restrict__ dep,
    const float* __restrict__ w_exp, const float* __restrict__ b_exp,
    const float* __restrict__ w_rq, const float* __restrict__ w_rk, const float* __restrict__ w_rv,
    const float* __restrict__ w_dq, const float* __restrict__ w_dk, const float* __restrict__ w_dv,
    bf16_t* __restrict__ Qb, bf16_t* __restrict__ Kb, bf16_t* __restrict__ VT)
{
    int tile = blockIdx.x;
    int z    = blockIdx.y;           // b*2 + strm
    int b = z >> 1, strm = z & 1;
    int sb = strm*2 + b;

    __shared__ float Xs[64][68];
    __shared__ float Ws[64][68];
    int tid = threadIdx.x;
    {
        int r = tid & 63, c0 = tid >> 6;
        stage_x_row(&Xs[r][0], rgb, dep, w_exp, b_exp, b, tile*64 + r, strm, c0, 4);
    }
    int sr = tid >> 4, sc = (tid & 15) * 4;
    int ty = tid >> 4, tx = tid & 15;

    #pragma unroll
    for (int m = 0; m < 3; ++m) {
        const float* W = strm ? (m == 0 ? w_dq : m == 1 ? w_dk : w_dv)
                              : (m == 0 ? w_rq : m == 1 ? w_rk : w_rv);
        __syncthreads();   // Xs ready (m=0) / prior GEMM done reading Ws (m>0)
        #pragma unroll
        for (int rr = 0; rr < 4; ++rr) {
            int r = rr*16 + sr;
            *(float4*)&Ws[r][sc] = *(const float4*)&W[r*64 + sc];
        }
        __syncthreads();

        float acc[4][4] = {};
        #pragma unroll
        for (int k = 0; k < 64; k += 4) {
            float4 xv[4], wv4[4];
            #pragma unroll
            for (int i = 0; i < 4; ++i) xv[i] = *(const float4*)&Xs[4*ty + i][k];
            #pragma unroll
            for (int j = 0; j < 4; ++j) wv4[j] = *(const float4*)&Ws[tx + 16*j][k];
            #pragma unroll
            for (int i = 0; i < 4; ++i)
                #pragma unroll
                for (int j = 0; j < 4; ++j)
                    acc[i][j] += xv[i].x*wv4[j].x + xv[i].y*wv4[j].y + xv[i].z*wv4[j].z + xv[i].w*wv4[j].w;
        }
        float scale = (m == 0) ? (0.35355339059327373f * 1.4426950408889634f) : 1.0f;
        #pragma unroll
        for (int j = 0; j < 4; ++j) {
            int o = tx + 16*j;
            int h = o >> 3, d = o & 7;
            #pragma unroll
            for (int i = 0; i < 4; ++i) {
                int n = tile*64 + 4*ty + i;
                bf16_t v = f2bf(acc[i][j] * scale);
                if (m == 0)      Qb[(((size_t)sb*8 + h)*NTOK + n)*8 + d] = v;
                else if (m == 1) Kb[(((size_t)sb*8 + h)*NTOK + n)*8 + d] = v;
                else             VT[(((size_t)sb*8 + h)*8 + d)*NTOK + n] = v;
            }
        }
    }
}

// MFMA flash attention. grid(36, 8, 4): qt-group x head x (b*2+which).
// 256 thr = 4 INDEPENDENT waves (no __syncthreads); wave w handles qtile
// blockIdx.x*4+w = 16 queries, looping 72 chunks of 32 keys:
//   S(16x32) = 2x mfma_16x16x32 (head dim in quad0, quads1-3 zero)
//   P = exp2(S) (no-max; proven) -> bf16 trunc -> per-wave LDS -> A-frag
//   O_aug(16x16) += P x V_aug  (V dims at n<8, ONES at n=8 -> l in col 8)
// Pls row stride 40 bf16 (80B): b128 read starts land on 8 distinct 4-bank
// groups, 2-way max (free) — fixes R14's 6.7M conflicts.
__global__ __launch_bounds__(256) void attn_kernel(
    const bf16_t* __restrict__ Qb, const bf16_t* __restrict__ Kb,
    const bf16_t* __restrict__ VT,
    float* __restrict__ AOr, float* __restrict__ AOd)
{
    int h = blockIdx.y;
    int z = blockIdx.z;
    int b = z >> 1, which = z & 1;
    int qsb = which * 2 + b;
    int ksb = (1 - which) * 2 + b;
    const bf16_t* Q  = Qb + ((size_t)qsb * 8 + h) * NTOK * 8;
    const bf16_t* K  = Kb + ((size_t)ksb * 8 + h) * NTOK * 8;
    const bf16_t* Vt = VT + ((size_t)ksb * 8 + h) * 8 * NTOK;  // [d][key]
    float* AO = which ? AOd : AOr;

    __shared__ __align__(16) bf16_t Pls[4][16][40];  // padded rows (5 KB)
    __shared__ __align__(16) float  Ols[4][16][16];  // per-wave O tiles (4 KB)

    int tid = threadIdx.x;
    int t = tid & 63, w = tid >> 6;
    int m16 = t & 15, quad = t >> 4;
    int qt = blockIdx.x * 4 + w;       // 0..143
    int n0 = qt * 16;

    const bf16x8 zf = {0,0,0,0,0,0,0,0};
    const bf16x8 onesf = {0x3F80,0x3F80,0x3F80,0x3F80,0x3F80,0x3F80,0x3F80,0x3F80};
    const f32x4 cz = {0.f, 0.f, 0.f, 0.f};

    // Q fragment: A[m=lane&15][k=quad*8+j]; only quad 0 (dims 0-7) real.
    bf16x8 qf = (quad == 0) ? *(const bf16x8*)&Q[(size_t)(n0 + m16) * 8] : zf;

    f32x4 oacc = cz;

    #pragma unroll 1
    for (int ck = 0; ck < 72; ++ck) {
        int k0 = ck * 32;
        bf16x8 kf0 = (quad == 0) ? *(const bf16x8*)&K[(size_t)(k0 + m16) * 8]      : zf;
        bf16x8 kf1 = (quad == 0) ? *(const bf16x8*)&K[(size_t)(k0 + 16 + m16) * 8] : zf;
        bf16x8 vf = (m16 < 8) ? *(const bf16x8*)&Vt[(size_t)m16 * NTOK + k0 + quad * 8]
                  : (m16 == 8 ? onesf : zf);

        f32x4 s0 = __builtin_amdgcn_mfma_f32_16x16x32_bf16(qf, kf0, cz, 0, 0, 0);
        f32x4 s1 = __builtin_amdgcn_mfma_f32_16x16x32_bf16(qf, kf1, cz, 0, 0, 0);

        #pragma unroll
        for (int r = 0; r < 4; ++r) {
            float p0 = __builtin_amdgcn_exp2f(s0[r]);
            float p1 = __builtin_amdgcn_exp2f(s1[r]);
            Pls[w][quad*4 + r][m16]      = (bf16_t)(__float_as_uint(p0) >> 16);
            Pls[w][quad*4 + r][m16 + 16] = (bf16_t)(__float_as_uint(p1) >> 16);
        }
        bf16x8 pf = *(const bf16x8*)&Pls[w][m16][quad * 8];
        oacc = __builtin_amdgcn_mfma_f32_16x16x32_bf16(pf, vf, oacc, 0, 0, 0);
    }

    #pragma unroll
    for (int r = 0; r < 4; ++r)
        Ols[w][quad*4 + r][m16] = oacc[r];
    #pragma unroll
    for (int e = 0; e < 2; ++e) {
        int idx = t * 2 + e;           // 0..127 = 16 q x 8 d
        int qq = idx >> 3, d = idx & 7;
        float val = Ols[w][qq][d] / Ols[w][qq][8];
        AO[((size_t)b * NTOK + n0 + qq) * 64 + 8 * h + d] = val;
    }
}

// Fused 2x K=64 GEMM (W1,W2) + beff + GELU + transposed store.
// grid(72, 2): 32-token tiles x batch. AO rows already normalized fp32.
__global__ __launch_bounds__(256) void outcomp_kernel(
    const float* __restrict__ AOr, const float* __restrict__ AOd,
    const float* __restrict__ W1, const float* __restrict__ W2,
    const float* __restrict__ beff, float* __restrict__ out)
{
    int tile = blockIdx.x;       // 0..71
    int b    = blockIdx.y;
    int n0 = tile * 32;
    __shared__ float Ar[32][68];
    __shared__ float Ad[32][68];
    __shared__ float W1s[64][68];
    __shared__ float W2s[64][68];
    int tid = threadIdx.x;
    #pragma unroll
    for (int pass = 0; pass < 2; ++pass) {
        int idx = tid + pass*256;
        int row = idx >> 4, c4 = (idx & 15) * 4;
        *(float4*)&Ar[row][c4] = *(const float4*)&AOr[((size_t)b*NTOK + n0 + row)*64 + c4];
        *(float4*)&Ad[row][c4] = *(const float4*)&AOd[((size_t)b*NTOK + n0 + row)*64 + c4];
    }
    {
        int sr = tid >> 4, sc4 = (tid & 15) * 4;
        #pragma unroll
        for (int rr = 0; rr < 4; ++rr) {
            int r = rr*16 + sr;
            *(float4*)&W1s[r][sc4] = *(const float4*)&W1[r*64 + sc4];
            *(float4*)&W2s[r][sc4] = *(const float4*)&W2[r*64 + sc4];
        }
    }
    __syncthreads();

    int tx = tid & 15, ty = tid >> 4;
    float g[2][4] = {};
    #pragma unroll
    for (int k = 0; k < 64; k += 4) {
        float4 xr0 = *(const float4*)&Ar[2*ty][k];
        float4 xr1 = *(const float4*)&Ar[2*ty + 1][k];
        float4 xd0 = *(const float4*)&Ad[2*ty][k];
        float4 xd1 = *(const float4*)&Ad[2*ty + 1][k];
        #pragma unroll
        for (int jj = 0; jj < 4; ++jj) {
            float4 w1 = *(const float4*)&W1s[tx + 16*jj][k];
            float4 w2 = *(const float4*)&W2s[tx + 16*jj][k];
            g[0][jj] += xr0.x*w1.x + xr0.y*w1.y + xr0.z*w1.z + xr0.w*w1.w
                      + xd0.x*w2.x + xd0.y*w2.y + xd0.z*w2.z + xd0.w*w2.w;
            g[1][jj] += xr1.x*w1.x + xr1.y*w1.y + xr1.z*w1.z + xr1.w*w1.w
                      + xd1.x*w2.x + xd1.y*w2.y + xd1.z*w2.z + xd1.w*w2.w;
        }
    }
    #pragma unroll
    for (int jj = 0; jj < 4; ++jj) {
        int o = tx + 16*jj;
        float be = beff[o];
        #pragma unroll
        for (int i = 0; i < 2; ++i) {
            int n = n0 + 2*ty + i;
            int wi = n / HH, hi = n % HH;
            float x = g[i][jj] + be;
            float gl = 0.5f * x * (1.0f + erff(x * 0.70710678118654752f));
            out[((b*C + o)*WW + wi)*HH + hi] = gl;
        }
    }
}

// ===========================================================================
// FALLBACK (R9 big path, proven): ws >= 3,538,944 B.
// ===========================================================================
__global__ __launch_bounds__(256) void kv_all_kernel(
    const float* __restrict__ rgb, const float* __restrict__ dep,
    const float* __restrict__ w_exp, const float* __restrict__ b_exp,
    const float* __restrict__ w_rk, const float* __restrict__ w_rv,
    const float* __restrict__ w_dk, const float* __restrict__ w_dv,
    bf16_t* __restrict__ Kr, bf16_t* __restrict__ Vr,
    bf16_t* __restrict__ Kd, bf16_t* __restrict__ Vd)
{
    int tile = blockIdx.x;
    int m    = blockIdx.y;
    int z    = blockIdx.z;
    int b = z >> 1, strm = z & 1;
    const float* W = strm ? (m ? w_dv : w_dk) : (m ? w_rv : w_rk);
    bf16_t* O = (strm ? (m ? Vd : Kd) : (m ? Vr : Kr))
              + ((size_t)b * NTOK + tile * 64) * 64;

    __shared__ float Xs[64][68];
    __shared__ float Ws[64][68];
    int tid = threadIdx.x;
    {
        int r = tid & 63, c0 = tid >> 6;
        stage_x_row(&Xs[r][0], rgb, dep, w_exp, b_exp, b, tile*64 + r, strm, c0, 4);
    }
    int sr = tid >> 4, sc = (tid & 15) * 4;
    #pragma unroll
    for (int rr = 0; rr < 4; ++rr) {
        int r = rr*16 + sr;
        *(float4*)&Ws[r][sc] = *(const float4*)&W[r*64 + sc];
    }
    __syncthreads();

    int ty = tid >> 4, tx = tid & 15;
    float acc[4][4] = {};
    #pragma unroll
    for (int k = 0; k < 64; k += 4) {
        float4 xv[4], wv4[4];
        #pragma unroll
        for (int i = 0; i < 4; ++i) xv[i] = *(const float4*)&Xs[4*ty + i][k];
        #pragma unroll
        for (int j = 0; j < 4; ++j) wv4[j] = *(const float4*)&Ws[tx + 16*j][k];
        #pragma unroll
        for (int i = 0; i < 4; ++i)
            #pragma unroll
            for (int j = 0; j < 4; ++j)
                acc[i][j] += xv[i].x*wv4[j].x + xv[i].y*wv4[j].y + xv[i].z*wv4[j].z + xv[i].w*wv4[j].w;
    }
    #pragma unroll
    for (int i = 0; i < 4; ++i)
        #pragma unroll
        for (int j = 0; j < 4; ++j)
            O[(4*ty + i)*64 + tx + 16*j] = f2bf(acc[i][j]);
}

__global__ __launch_bounds__(256) void attn_all_kernel(
    const float* __restrict__ rgb, const float* __restrict__ dep,
    const float* __restrict__ w_exp, const float* __restrict__ b_exp,
    const float* __restrict__ w_rq, const float* __restrict__ w_dq,
    const bf16_t* __restrict__ Kr, const bf16_t* __restrict__ Vr,
    const bf16_t* __restrict__ Kd, const bf16_t* __restrict__ Vd,
    bf16_t* __restrict__ AOr, bf16_t* __restrict__ AOd)
{
    int qt = blockIdx.x;
    int h  = blockIdx.y;
    int z  = blockIdx.z;
    int b = z >> 1, which = z & 1;
    const float* wq = which ? w_dq : w_rq;
    const bf16_t* K = which ? Kr : Kd;
    const bf16_t* V = which ? Vr : Vd;
    bf16_t* AO      = which ? AOd : AOr;

    __shared__ float Xs[64][68];
    __shared__ float Wqs[8][64];
    __shared__ __align__(16) float Ks[4][64][KVSTRIDE];
    __shared__ __align__(16) float Vs[4][64][KVSTRIDE];

    int tid = threadIdx.x;
    int t = tid & 63;
    int w = tid >> 6;
    int n = qt * 64 + t;

    stage_x_row(&Xs[t][0], rgb, dep, w_exp, b_exp, b, n, which == 0 ? 0 : 1, w, 4);
    if (w == 0) {
        #pragma unroll
        for (int d = 0; d < 8; ++d) Wqs[d][t] = wq[(8*h + d)*64 + t];
    }
    __syncthreads();

    const float sc = 0.35355339059327373f * 1.4426950408889634f;
    float q[8];
    #pragma unroll
    for (int d = 0; d < 8; ++d) {
        float s = 0.f;
        #pragma unroll 8
        for (int c = 0; c < 64; ++c) s += Xs[t][c] * Wqs[d][c];
        q[d] = s * sc;
    }

    float mrun = -INFINITY, l = 0.f;
    float acc[8] = {};

    #pragma unroll 1
    for (int st = 0; st < 9; ++st) {
        __syncthreads();
        {
            size_t g = ((size_t)b * NTOK + (w*576 + st*64 + t)) * 64 + 8 * h;
            *(float4*)&Ks[w][t][0] = ld_bf4(&K[g]);
            *(float4*)&Ks[w][t][4] = ld_bf4(&K[g + 4]);
            *(float4*)&Vs[w][t][0] = ld_bf4(&V[g]);
            *(float4*)&Vs[w][t][4] = ld_bf4(&V[g + 4]);
        }
        __syncthreads();

        for (int g8 = 0; g8 < 8; ++g8) {
            float s[8];
            #pragma unroll
            for (int u = 0; u < 8; ++u) {
                const float4 ka = *(const float4*)&Ks[w][g8*8 + u][0];
                const float4 kb = *(const float4*)&Ks[w][g8*8 + u][4];
                s[u] = q[0]*ka.x + q[1]*ka.y + q[2]*ka.z + q[3]*ka.w
                     + q[4]*kb.x + q[5]*kb.y + q[6]*kb.z + q[7]*kb.w;
            }
            float tm = fmaxf(fmaxf(fmaxf(s[0],s[1]), fmaxf(s[2],s[3])),
                             fmaxf(fmaxf(s[4],s[5]), fmaxf(s[6],s[7])));
            float mn = fmaxf(mrun, tm);
            float alpha = __builtin_amdgcn_exp2f(mrun - mn);
            float ps = 0.f;
            #pragma unroll
            for (int u = 0; u < 8; ++u) { s[u] = __builtin_amdgcn_exp2f(s[u] - mn); ps += s[u]; }
            l = l * alpha + ps;
            #pragma unroll
            for (int d = 0; d < 8; ++d) acc[d] *= alpha;
            #pragma unroll
            for (int u = 0; u < 8; ++u) {
                const float4 va = *(const float4*)&Vs[w][g8*8 + u][0];
                const float4 vb = *(const float4*)&Vs[w][g8*8 + u][4];
                acc[0] += s[u]*va.x; acc[1] += s[u]*va.y; acc[2] += s[u]*va.z; acc[3] += s[u]*va.w;
                acc[4] += s[u]*vb.x; acc[5] += s[u]*vb.y; acc[6] += s[u]*vb.z; acc[7] += s[u]*vb.w;
            }
            mrun = mn;
        }
    }

    float* part = &Xs[0][0];
    __syncthreads();
    {
        float* p = &part[(w*64 + t) * 10];
        p[0] = mrun; p[1] = l;
        #pragma unroll
        for (int d = 0; d < 8; ++d) p[2 + d] = acc[d];
    }
    __syncthreads();
    if (tid < 64) {
        float M = -INFINITY;
        #pragma unroll
        for (int v = 0; v < 4; ++v) M = fmaxf(M, part[(v*64 + t)*10]);
        float L = 0.f, o[8] = {};
        #pragma unroll
        for (int v = 0; v < 4; ++v) {
            const float* p = &part[(v*64 + t)*10];
            float al = __builtin_amdgcn_exp2f(p[0] - M);
            L += p[1] * al;
            #pragma unroll
            for (int d = 0; d < 8; ++d) o[d] += p[2 + d] * al;
        }
        float inv = 1.0f / L;
        uint4 ov;
        ov.x = pack2(o[0]*inv, o[1]*inv);
        ov.y = pack2(o[2]*inv, o[3]*inv);
        ov.z = pack2(o[4]*inv, o[5]*inv);
        ov.w = pack2(o[6]*inv, o[7]*inv);
        *(uint4*)&AO[((size_t)b * NTOK + n) * 64 + 8 * h] = ov;
    }
}

__global__ __launch_bounds__(256) void projcomp_all_kernel(
    const bf16_t* __restrict__ AOr, const bf16_t* __restrict__ AOd,
    const float* __restrict__ w_rp, const float* __restrict__ b_rp,
    const float* __restrict__ w_dp, const float* __restrict__ b_dp,
    const float* __restrict__ w_comp, const float* __restrict__ b_comp,
    float* __restrict__ out)
{
    int tile = blockIdx.x;
    int b    = blockIdx.y;
    __shared__ float A[64][68];
    __shared__ float Bf[64][68];
    __shared__ float Pf[64][68];
    int tid = threadIdx.x;
    int sr = tid >> 4, sc = (tid & 15) * 4;
    int ty = tid >> 4, tx = tid & 15;
    float G[4][4] = {};

    #pragma unroll
    for (int half = 0; half < 2; ++half) {
        const bf16_t* AOx = half ? AOd : AOr;
        const float* Wp   = half ? w_dp : w_rp;
        const float* bp   = half ? b_dp : b_rp;
        #pragma unroll
        for (int rr = 0; rr < 4; ++rr) {
            int r = rr*16 + sr;
            *(float4*)&A[r][sc]  = ld_bf4(&AOx[((size_t)b*NTOK + tile*64 + r)*64 + sc]);
            *(float4*)&Bf[r][sc] = *(const float4*)&Wp[r*64 + sc];
        }
        __syncthreads();
        float acc[4][4] = {};
        #pragma unroll
        for (int k = 0; k < 64; k += 4) {
            float4 xv[4], wv[4];
            #pragma unroll
            for (int i = 0; i < 4; ++i) xv[i] = *(const float4*)&A[4*ty + i][k];
            #pragma unroll
            for (int j = 0; j < 4; ++j) wv[j] = *(const float4*)&Bf[tx + 16*j][k];
            #pragma unroll
            for (int i = 0; i < 4; ++i)
                #pragma unroll
                for (int j = 0; j < 4; ++j)
                    acc[i][j] += xv[i].x*wv[j].x + xv[i].y*wv[j].y + xv[i].z*wv[j].z + xv[i].w*wv[j].w;
        }
        __syncthreads();
        #pragma unroll
        for (int j = 0; j < 4; ++j) {
            float bj = bp[tx + 16*j];
            #pragma unroll
            for (int i = 0; i < 4; ++i)
                Pf[4*ty + i][tx + 16*j] = acc[i][j] + bj;
        }
        #pragma unroll
        for (int rr = 0; rr < 4; ++rr) {
            int r = rr*16 + sr;
            *(float4*)&Bf[r][sc] = *(const float4*)&w_comp[r*128 + half*64 + sc];
        }
        __syncthreads();
        #pragma unroll
        for (int k = 0; k < 64; k += 4) {
            float4 xv[4], wv[4];
            #pragma unroll
            for (int i = 0; i < 4; ++i) xv[i] = *(const float4*)&Pf[4*ty + i][k];
            #pragma unroll
            for (int j = 0; j < 4; ++j) wv[j] = *(const float4*)&Bf[tx + 16*j][k];
            #pragma unroll
            for (int i = 0; i < 4; ++i)
                #pragma unroll
                for (int j = 0; j < 4; ++j)
                    G[i][j] += xv[i].x*wv[j].x + xv[i].y*wv[j].y + xv[i].z*wv[j].z + xv[i].w*wv[j].w;
        }
        __syncthreads();
    }

    #pragma unroll
    for (int j = 0; j < 4; ++j) {
        int o = tx + 16*j;
        float bj = b_comp[o];
        #pragma unroll
        for (int i = 0; i < 4; ++i) {
            int n = tile*64 + 4*ty + i;
            int wi = n / HH, hi = n % HH;
            float x = G[i][j] + bj;
            float g = 0.5f * x * (1.0f + erff(x * 0.70710678118654752f));
            out[((b*C + o)*WW + wi)*HH + hi] = g;
        }
    }
}

// ---------------------------------------------------------------------------
extern "C" void kernel_launch(void* const* d_in, const int* in_sizes, int n_in,
                              void* d_out, int out_size, void* d_ws, size_t ws_size,
                              hipStream_t stream) {
    const float* rgb_fea = (const float*)d_in[0];
    const float* depth   = (const float*)d_in[1];
    const float* w_exp   = (const float*)d_in[2];
    const float* b_exp   = (const float*)d_in[3];
    const float* w_rq    = (const float*)d_in[4];
    const float* w_rk    = (const float*)d_in[5];
    const float* w_rv    = (const float*)d_in[6];
    const float* w_dq    = (const float*)d_in[7];
    const float* w_dk    = (const float*)d_in[8];
    const float* w_dv    = (const float*)d_in[9];
    const float* w_rp    = (const float*)d_in[10];
    const float* b_rp    = (const float*)d_in[11];
    const float* w_dp    = (const float*)d_in[12];
    const float* b_dp    = (const float*)d_in[13];
    const float* w_comp  = (const float*)d_in[14];
    const float* b_comp  = (const float*)d_in[15];
    float* out = (float*)d_out;

    if (ws_size >= 5931264) {
        char* Wb = (char*)d_ws;
        bf16_t* Qb  = (bf16_t*)Wb;                 // [4][8][2304][8] bf16
        bf16_t* Kb  = (bf16_t*)(Wb + 1179648);     // [4][8][2304][8] bf16
        bf16_t* VT  = (bf16_t*)(Wb + 2359296);     // [4][8][8][2304] bf16
        float* AOr  = (float*)(Wb + 3538944);      // [2][2304][64] fp32
        float* AOd  = (float*)(Wb + 4718592);
        float* W1   = (float*)(Wb + 5898240);
        float* W2   = (float*)(Wb + 5914624);
        float* beff = (float*)(Wb + 5931008);

        wprep_kernel<<<dim3(4, 2), dim3(256), 0, stream>>>(
            w_rp, w_dp, w_comp, b_rp, b_dp, b_comp, W1, W2, beff);
        qkv_kernel<<<dim3(36, 4), dim3(256), 0, stream>>>(
            rgb_fea, depth, w_exp, b_exp,
            w_rq, w_rk, w_rv, w_dq, w_dk, w_dv, Qb, Kb, VT);
        attn_kernel<<<dim3(36, 8, 4), dim3(256), 0, stream>>>(
            Qb, Kb, VT, AOr, AOd);
        outcomp_kernel<<<dim3(72, 2), dim3(256), 0, stream>>>(
            AOr, AOd, W1, W2, beff, out);
    } else {
        // R9 big path (proven)
        const size_t BUF = (size_t)BATCH * NTOK * 64;
        bf16_t* Kr  = (bf16_t*)d_ws;
        bf16_t* Vr  = Kr + BUF;
        bf16_t* Kd  = Vr + BUF;
        bf16_t* Vd  = Kd + BUF;
        bf16_t* AOr = Vd + BUF;
        bf16_t* AOd = AOr + BUF;
        kv_all_kernel<<<dim3(36, 2, 4), dim3(256), 0, stream>>>(
            rgb_fea, depth, w_exp, b_exp, w_rk, w_rv, w_dk, w_dv, Kr, Vr, Kd, Vd);
        attn_all_kernel<<<dim3(36, 8, 4), dim3(256), 0, stream>>>(
            rgb_fea, depth, w_exp, b_exp, w_rq, w_dq, Kr, Vr, Kd, Vd, AOr, AOd);
        projcomp_all_kernel<<<dim3(36, 2), dim3(256), 0, stream>>>(
            AOr, AOd, w_rp, b_rp, w_dp, b_dp, w_comp, b_comp, out);
    }
}